// Round 1
// 7135.110 us; speedup vs baseline: 1.7800x; 1.7800x over previous
//
#include <hip/hip_runtime.h>
#include <cstdint>
#include <cstddef>

#define NBLK 256
#define NTHR 512
#define B_ 64
#define P_ 196
#define E_ 512
#define A_ 512
#define D_ 512
#define M_ 512
#define V_ 1000
#define L_ 257
#define T_ 256

#define OUT_PRED  0
#define OUT_CAPS  (B_*T_*V_)                 /* 16,384,000 */
#define OUT_ALPHA (OUT_CAPS + B_*L_)         /* 16,400,448 */
#define OUT_SORT  (OUT_ALPHA + B_*T_*P_)     /* 19,611,712 */

typedef _Float16 h2 __attribute__((ext_vector_type(2)));

struct KP {
  const float* enc; const int* caps; const int* clen;
  const float* emb;
  const float* eaw; const float* eab;
  const float* daw; const float* dab;
  const float* faw; const float* fab;
  const float* wih; const float* bih;
  const float* whh; const float* bhh;
  const float* ihw; const float* ihb;
  const float* icw; const float* icb;
  const float* fbw; const float* fbb;
  const float* fcw; const float* fcb;
  float* out;
  int* bar; int* tb; int* sy;
  int* sort_ind; int* dec_len;
  float* mnT; float* hA; float* hB; float* hnG;
  float* a2G; float* gateG; float* xG; float* eG; float* att1;
  unsigned* wA2; unsigned* wG2;
};

__device__ __forceinline__ float sigf(float x){ return 1.f/(1.f+__expf(-x)); }
__device__ __forceinline__ float tanhf_(float x){
  float ax = fabsf(x);
  float e = __expf(-2.f*ax);
  float r = (1.f-e)/(1.f+e);
  return x < 0.f ? -r : r;
}
__device__ __forceinline__ unsigned short f2bf(float x){
  unsigned u = __float_as_uint(x);
  unsigned r = (u + 0x7fffu + ((u >> 16) & 1u)) >> 16;   // RNE
  return (unsigned short)r;
}
__device__ __forceinline__ float fdot2f(h2 a, h2 b, float c){
#if __has_builtin(__builtin_amdgcn_fdot2)
  return __builtin_amdgcn_fdot2(a, b, c, false);
#else
  return c + (float)a.x*(float)b.x + (float)a.y*(float)b.y;
#endif
}
__device__ __forceinline__ unsigned packh2(float a, float b){
  h2 v; v.x = (_Float16)a; v.y = (_Float16)b;
  return __builtin_bit_cast(unsigned, v);
}
__device__ __forceinline__ h2 ash2(unsigned u){ return __builtin_bit_cast(h2, u); }

#define LD_A(p)     __hip_atomic_load((p), __ATOMIC_RELAXED, __HIP_MEMORY_SCOPE_AGENT)
#define ST_A(p,v)   __hip_atomic_store((p),(v), __ATOMIC_RELAXED, __HIP_MEMORY_SCOPE_AGENT)
#define ST_REL(p,v) __hip_atomic_store((p),(v), __ATOMIC_RELEASE, __HIP_MEMORY_SCOPE_AGENT)
#define FAA(p)      __hip_atomic_fetch_add((p),1, __ATOMIC_RELAXED, __HIP_MEMORY_SCOPE_AGENT)
__device__ __forceinline__ float ldg_c(const float* p){
  return __hip_atomic_load(p, __ATOMIC_RELAXED, __HIP_MEMORY_SCOPE_AGENT);
}
__device__ __forceinline__ float2 ldg2_c(const float* p){
  unsigned long long u = __hip_atomic_load((const unsigned long long*)p,
                       __ATOMIC_RELAXED, __HIP_MEMORY_SCOPE_AGENT);
  return __builtin_bit_cast(float2, u);
}
__device__ __forceinline__ void stg_c(float* p, float v){
  __hip_atomic_store(p, v, __ATOMIC_RELAXED, __HIP_MEMORY_SCOPE_AGENT);
}

// Fenced grid barrier -- pre-phase only.
__device__ __forceinline__ void gridbar(int* bar, int blk){
  __syncthreads();
  if (threadIdx.x == 0){
    __builtin_amdgcn_fence(__ATOMIC_RELEASE, "agent");
    int s = LD_A(&bar[144]);
    int* leaf = &bar[(blk & 7)*16];
    if (FAA(leaf) == 31){
      ST_A(leaf, 0);
      if (FAA(&bar[128]) == 7){
        ST_A(&bar[128], 0);
        ST_REL(&bar[144], s+1);
      }
    }
    while (LD_A(&bar[144]) == s) __builtin_amdgcn_s_sleep(2);
    __builtin_amdgcn_fence(__ATOMIC_ACQUIRE, "agent");
  }
  __syncthreads();
}

// Monotonic fence-free tree barrier for the time loop.
__device__ __forceinline__ void treebar(int* tb, int blk, int ep){
  __syncthreads();
  if (threadIdx.x == 0){
    int* leaf = &tb[(blk & 7)*16];
    int prev = FAA(leaf);
    if (prev == ep*32 - 1){
      int pr = FAA(&tb[128]);
      if (pr == ep*8 - 1) ST_A(&tb[144], ep);
    }
    while (LD_A(&tb[144]) < ep) __builtin_amdgcn_s_sleep(2);
    asm volatile("" ::: "memory");
  }
  __syncthreads();
}

// One weight-uint2 (4 k-elems) x 2 batches (uint4 from transposed x in LDS).
#define ACC2(a0,a1,xx) \
  a0 = fdot2f(ash2(w.x), ash2(xx.x), a0); \
  a0 = fdot2f(ash2(w.y), ash2(xx.y), a0); \
  a1 = fdot2f(ash2(w.x), ash2(xx.z), a1); \
  a1 = fdot2f(ash2(w.y), ash2(xx.w), a1);

// LDS map (147.5 KB):
//   [0,      50176) att1L  bf16[49][512]  resident (P2 identity: b=blk>>2,q=blk&3)
//   [50176, 105472) encT2  h2[512][27]    resident
//   [105472,107520) fwL    f32[512]       resident
//   [107520,108032) cL     f32[16][8]     persistent LSTM cell slice (P3 identity)
//   [108032,   ...) SCRATCH (phase-local, aliased):
//     GEMM phases: xT2 uint2[k4][8bb]  (P1: 8KB, P3: 24KB) at +0
//                  redW f32[8w][8bb][64c] (16KB) at +24576
//                  gLs  f32[512] (2KB) at +40960 (P3 only)
//     P2: a2L[512] gateL[512] eL[256] alphaL[256] alpha2L[32] at +0
// Pre1 tile GEMM aliases [0, 76032) -- dead before residents are written.
//
// K-split GEMM scheme (replaces wave=batch scheme): the 8 waves of a block
// split K 8 ways; each thread holds acc[8] (one per batch of its bt-octet),
// reads each weight uint2 ONCE per block (8x less L2/LLC weight traffic),
// broadcasts x from transposed LDS (uniform-address ds_read_b128 = free),
// then reduces wave partials through redW.
__global__ __launch_bounds__(NTHR, 2) void dec_kernel(KP p){
  __shared__ __align__(16) char smem_raw[151040];
  unsigned short* att1L = (unsigned short*)smem_raw;
  unsigned* encT2  = (unsigned*)(smem_raw + 50176);
  float* fwL       = (float*)(smem_raw + 105472);
  float* cL        = (float*)(smem_raw + 107520);
  char* SCR        = smem_raw + 108032;
  uint2* xT2       = (uint2*)SCR;                    // transposed packed x
  const uint4* xT4 = (const uint4*)SCR;              // same buffer, b128 view
  float* redW      = (float*)(SCR + 24576);          // wave partials 16KB
  float* gLs       = (float*)(SCR + 40960);          // P3 gate sums 2KB
  float* a2L       = (float*)SCR;                    // P2
  float* gateL     = (float*)(SCR + 2048);
  float* eL        = (float*)(SCR + 4096);
  float* alphaL    = (float*)(SCR + 5120);
  unsigned* alpha2L= (unsigned*)(SCR + 6144);

  const int blk  = blockIdx.x;
  const int tid  = threadIdx.x;
  const int lane = tid & 63;
  const int wave = tid >> 6;
  // P2 identity
  const int b    = blk >> 2;
  const int q    = blk & 3;
  // P1/P3 identity: column-tile x batch-octet
  const int ct   = blk & 31;          // 0..31
  const int bt   = blk >> 5;          // 0..7

  // ---------------- Pre0: stable descending argsort + caps gather ----------------
  if (blk == 0){
    if (tid < B_){
      int lb = p.clen[tid];
      int rank = 0;
      for (int j = 0; j < B_; j++){
        int lj = p.clen[j];
        rank += (lj > lb) || (lj == lb && j < tid);
      }
      p.sort_ind[rank] = tid;
      p.dec_len[rank]  = lb - 1;
      p.out[OUT_SORT + rank] = (float)tid;
    }
    __syncthreads();
    for (int idx = tid; idx < B_*L_; idx += NTHR){
      int bb = idx / L_;
      int l = idx - bb*L_;
      int sbv = p.sort_ind[bb];
      p.out[OUT_CAPS + idx] = (float)p.caps[sbv*L_ + l];
    }
  }
  gridbar(p.bar, blk);

  const int sb  = p.sort_ind[b];
  const int dlb = p.dec_len[b];

  // ---------------- Pre1: att1 = enc_s @ enc_att_w^T + b (196 tiles) + mean (64) ----------------
  for (int task = blk; task < 260; task += NBLK){
    if (task < 196){
      const int r0 = task*64;
      float* wL = (float*)smem_raw;             // [512][33]
      float* eLt = (float*)smem_raw + 512*33;   // [64][33]
      const int tx = tid & 31, ty = tid >> 5;   // ty<16
      float acc[4][16];
      #pragma unroll
      for (int i=0;i<4;i++)
        #pragma unroll
        for (int j=0;j<16;j++) acc[i][j] = 0.f;
      for (int k0 = 0; k0 < 512; k0 += 32){
        __syncthreads();
        for (int i = tid; i < 512*32; i += NTHR){
          int a = i >> 5, kk = i & 31;
          wL[a*33 + kk] = p.eaw[a*512 + k0 + kk];
        }
        for (int i = tid; i < 64*32; i += NTHR){
          int rl = i >> 5, kk = i & 31;
          int r = r0 + rl;
          int bb = r / 196;
          int pp = r - bb*196;
          int sbv = p.sort_ind[bb];
          eLt[rl*33 + kk] = p.enc[((size_t)sbv*196 + pp)*512 + k0 + kk];
        }
        __syncthreads();
        for (int kk = 0; kk < 32; kk++){
          float ev[4];
          #pragma unroll
          for (int ii=0;ii<4;ii++) ev[ii] = eLt[(ty*4+ii)*33 + kk];
          #pragma unroll
          for (int jj=0;jj<16;jj++){
            float wv = wL[(tx + 32*jj)*33 + kk];
            #pragma unroll
            for (int ii=0;ii<4;ii++) acc[ii][jj] = fmaf(ev[ii], wv, acc[ii][jj]);
          }
        }
      }
      #pragma unroll
      for (int jj=0;jj<16;jj++){
        int a = tx + 32*jj;
        float bbv = p.eab[a];
        #pragma unroll
        for (int ii=0;ii<4;ii++){
          int r = r0 + ty*4 + ii;
          p.att1[(size_t)r*512 + a] = acc[ii][jj] + bbv;
        }
      }
      __syncthreads();
    } else {
      int bb = task - 196;
      int sbv = p.sort_ind[bb];
      const float* eb = p.enc + (size_t)sbv*P_*E_;
      for (int e = tid; e < E_; e += NTHR){
        float s = 0.f;
        for (int pp = 0; pp < P_; pp++) s += eb[pp*E_ + e];
        p.mnT[bb*512 + e] = s * (1.f/196.f);
      }
    }
  }
  gridbar(p.bar, blk);

  // ---------------- Pre2: residents + f16 weight tables + h0/c0 ----------------
  // (a) P2 residents
  for (int idx = tid; idx < 49*512; idx += NTHR){
    int pp = idx >> 9, a = idx & 511;
    att1L[idx] = f2bf(p.att1[((size_t)(b*196 + q*49 + pp))*512 + a]);
  }
  for (int i = tid; i < 512*25; i += NTHR){
    int p2 = i >> 9, e = i & 511;
    int pr0 = q*49 + 2*p2;
    float e0 = p.enc[((size_t)sb*196 + pr0)*512 + e];
    float e1 = (2*p2+1 < 49) ? p.enc[((size_t)sb*196 + pr0 + 1)*512 + e] : 0.f;
    encT2[e*27 + p2] = packh2(e0, e1);
  }
  fwL[tid] = p.faw[tid];
  // (b) wA2: k2-slice = blk; vcols: 0-511 daw, 512-1023 fbw, 1024-2023 fcw
  {
    int k2 = blk, k = 2*k2;
    for (int vc = tid; vc < 2048; vc += NTHR){
      float w0 = 0.f, w1 = 0.f;
      if (vc < 512){ const float* r = p.daw + (size_t)vc*512 + k; w0 = r[0]; w1 = r[1]; }
      else if (vc < 1024){ const float* r = p.fbw + (size_t)(vc-512)*512 + k; w0 = r[0]; w1 = r[1]; }
      else if (vc < 2024){ const float* r = p.fcw + (size_t)(vc-1024)*512 + k; w0 = r[0]; w1 = r[1]; }
      p.wA2[((size_t)(k2>>1)*2048 + vc)*2 + (k2&1)] = packh2(w0, w1);
    }
  }
  // (c) wG2: k2-slices blk*3..+2; col c = j*4+g -> row g*512+j
  for (int s = 0; s < 3; s++){
    int k2 = blk*3 + s, k = 2*k2;
    for (int c = tid; c < 2048; c += NTHR){
      int j = c >> 2, g = c & 3, r = g*512 + j;
      float w0, w1;
      if (k2 < 512){ const float* rr = p.wih + (size_t)r*1024 + k; w0 = rr[0]; w1 = rr[1]; }
      else         { const float* rr = p.whh + (size_t)r*512 + (k-1024); w0 = rr[0]; w1 = rr[1]; }
      p.wG2[((size_t)(k2>>1)*2048 + c)*2 + (k2&1)] = packh2(w0, w1);
    }
  }
  // (d) h0/c0 for P3 slice (ct: 16 j's, bt: 8 b's)
  if (tid < 128){
    int jj = tid >> 3, bb2 = tid & 7;
    int b8 = bt*8 + bb2, jg = ct*16 + jj;
    const float* mrow = p.mnT + b8*512;
    const float* hw = p.ihw + (size_t)jg*512;
    const float* cw = p.icw + (size_t)jg*512;
    float ah = 0.f, ac = 0.f;
    for (int k = 0; k < 512; k++){ ah = fmaf(hw[k], mrow[k], ah); ac = fmaf(cw[k], mrow[k], ac); }
    stg_c(&p.hA[b8*512 + jg], ah + p.ihb[jg]);
    cL[jj*8 + bb2] = ac + p.icb[jg];
  }
  gridbar(p.bar, blk);

  const float fab0 = p.fab[0];
  int ep = 0;

  // ---------------- time loop: 3 fence-free grid bars + 1 group sync ----------------
  for (int t = 0; t < T_; t++){
    const float* hR = (t & 1) ? p.hB : p.hA;   // h(t)
    float*       hW = (t & 1) ? p.hA : p.hB;   // h(t+1)

    // ======== P1: a2+gate (ct<16) | preds(t-1) (ct>=16) ========
    // K-split: wave w does k4 in [w*16, w*16+16); acc[8] = 8 batches.
    if (ct < 16){
      for (int idx = tid; idx < 1024; idx += NTHR){
        int bb2 = idx & 7, k4 = idx >> 3;
        const float* src = &hR[(bt*8 + bb2)*512 + 4*k4];
        float2 v0 = ldg2_c(src), v1 = ldg2_c(src + 2);
        uint2 u; u.x = packh2(v0.x, v0.y); u.y = packh2(v1.x, v1.y);
        xT2[idx] = u;                      // xT2[k4*8+bb]
      }
      __syncthreads();
      const int vc = ct*64 + lane;
      const uint2* wa = (const uint2*)p.wA2;
      float acc[8];
      #pragma unroll
      for (int i = 0; i < 8; i++) acc[i] = 0.f;
      const int k40 = wave*16;
      #pragma unroll 4
      for (int k4 = k40; k4 < k40 + 16; k4++){
        uint2 w = wa[k4*2048 + vc];
        uint4 x0 = xT4[k4*4+0], x1 = xT4[k4*4+1];
        uint4 x2 = xT4[k4*4+2], x3 = xT4[k4*4+3];
        ACC2(acc[0],acc[1],x0); ACC2(acc[2],acc[3],x1);
        ACC2(acc[4],acc[5],x2); ACC2(acc[6],acc[7],x3);
      }
      #pragma unroll
      for (int bb2 = 0; bb2 < 8; bb2++) redW[wave*512 + bb2*64 + lane] = acc[bb2];
      __syncthreads();
      {
        int bb2 = tid >> 6, l = tid & 63;
        float s = 0.f;
        #pragma unroll
        for (int w8 = 0; w8 < 8; w8++) s += redW[w8*512 + bb2*64 + l];
        int b8 = bt*8 + bb2, vcl = ct*64 + l;
        if (vcl < 512) stg_c(&p.a2G[b8*512 + vcl], s + p.dab[vcl]);
        else           stg_c(&p.gateG[b8*512 + (vcl-512)], sigf(s + p.fbb[vcl-512]));
      }
    } else if (t > 0){
      for (int idx = tid; idx < 1024; idx += NTHR){
        int bb2 = idx & 7, k4 = idx >> 3;
        const float* src = &p.hnG[(bt*8 + bb2)*512 + 4*k4];
        float2 v0 = ldg2_c(src), v1 = ldg2_c(src + 2);
        uint2 u; u.x = packh2(v0.x, v0.y); u.y = packh2(v1.x, v1.y);
        xT2[idx] = u;
      }
      __syncthreads();
      const int vv = 1024 + (ct-16)*64 + lane;   // fcw columns (zeros >= 2024)
      const uint2* wa = (const uint2*)p.wA2;
      float acc[8];
      #pragma unroll
      for (int i = 0; i < 8; i++) acc[i] = 0.f;
      const int k40 = wave*16;
      #pragma unroll 4
      for (int k4 = k40; k4 < k40 + 16; k4++){
        uint2 w = wa[k4*2048 + vv];
        uint4 x0 = xT4[k4*4+0], x1 = xT4[k4*4+1];
        uint4 x2 = xT4[k4*4+2], x3 = xT4[k4*4+3];
        ACC2(acc[0],acc[1],x0); ACC2(acc[2],acc[3],x1);
        ACC2(acc[4],acc[5],x2); ACC2(acc[6],acc[7],x3);
      }
      #pragma unroll
      for (int bb2 = 0; bb2 < 8; bb2++) redW[wave*512 + bb2*64 + lane] = acc[bb2];
      __syncthreads();
      {
        int bb2 = tid >> 6, l = tid & 63;
        int v2 = (ct-16)*64 + l;
        if (v2 < 1000){
          float s = 0.f;
          #pragma unroll
          for (int w8 = 0; w8 < 8; w8++) s += redW[w8*512 + bb2*64 + l];
          int b8 = bt*8 + bb2;
          bool mm = (t-1) < p.dec_len[b8];
          p.out[OUT_PRED + ((size_t)b8*T_ + (t-1))*V_ + v2] = mm ? (s + p.fcb[v2]) : 0.f;
        }
      }
    }
    treebar(p.tb, blk, ++ep);   // B1

    // ======== P2: attention (group of 4 blocks per b) ========
    {
      a2L[tid]   = ldg_c(&p.a2G[b*512 + tid]);
      gateL[tid] = ldg_c(&p.gateG[b*512 + tid]);
      if (tid < 128) stg_c(&p.xG[b*1024 + 512 + q*128 + tid], 0.f);
      {
        int cap = p.caps[sb*L_ + t];
        if (tid < 128)
          stg_c(&p.xG[b*1024 + q*128 + tid], p.emb[(size_t)cap*M_ + q*128 + tid]);
      }
      __syncthreads();
      // e for own 49 rows from bf16 att1L
      {
        float4 aA = ((float4*)a2L)[lane*2], aB = ((float4*)a2L)[lane*2+1];
        float4 fA = ((float4*)fwL)[lane*2], fB = ((float4*)fwL)[lane*2+1];
        for (int pp = wave; pp < 49; pp += 8){
          uint4 raw = ((const uint4*)att1L)[pp*64 + lane];
          float s =
            fmaxf(__uint_as_float(raw.x << 16)        + aA.x, 0.f)*fA.x +
            fmaxf(__uint_as_float(raw.x & 0xffff0000u)+ aA.y, 0.f)*fA.y +
            fmaxf(__uint_as_float(raw.y << 16)        + aA.z, 0.f)*fA.z +
            fmaxf(__uint_as_float(raw.y & 0xffff0000u)+ aA.w, 0.f)*fA.w +
            fmaxf(__uint_as_float(raw.z << 16)        + aB.x, 0.f)*fB.x +
            fmaxf(__uint_as_float(raw.z & 0xffff0000u)+ aB.y, 0.f)*fB.y +
            fmaxf(__uint_as_float(raw.w << 16)        + aB.z, 0.f)*fB.z +
            fmaxf(__uint_as_float(raw.w & 0xffff0000u)+ aB.w, 0.f)*fB.w;
          #pragma unroll
          for (int o = 32; o > 0; o >>= 1) s += __shfl_down(s, o);
          if (lane == 0) stg_c(&p.eG[b*256 + q*49 + pp], s + fab0);
        }
      }
      // group sync: e complete (also orders xG zero vs atomicAdd below)
      __syncthreads();
      if (tid == 0){
        FAA(&p.sy[b*16]);
        while (LD_A(&p.sy[b*16]) < 4*(t+1)) __builtin_amdgcn_s_sleep(1);
        asm volatile("" ::: "memory");
      }
      __syncthreads();
      if (tid < 196) eL[tid] = ldg_c(&p.eG[b*256 + tid]);
      __syncthreads();
      if (wave == 0){
        float mx = -1e30f;
        for (int i = lane; i < P_; i += 64) mx = fmaxf(mx, eL[i]);
        #pragma unroll
        for (int o = 32; o > 0; o >>= 1) mx = fmaxf(mx, __shfl_xor(mx, o));
        float sum = 0.f;
        for (int i = lane; i < P_; i += 64){
          float ex = __expf(eL[i] - mx);
          alphaL[i] = ex;
          sum += ex;
        }
        #pragma unroll
        for (int o = 32; o > 0; o >>= 1) sum += __shfl_xor(sum, o);
        float inv = 1.f / sum;
        for (int i = lane; i < P_; i += 64) alphaL[i] *= inv;
      }
      __syncthreads();
      {
        bool mb = t < dlb;
        if (tid < 49)
          p.out[OUT_ALPHA + ((size_t)b*T_ + t)*P_ + q*49 + tid] = mb ? alphaL[q*49 + tid] : 0.f;
        if (tid < 25){
          float a0 = alphaL[q*49 + 2*tid];
          float a1 = (2*tid+1 < 49) ? alphaL[q*49 + 2*tid + 1] : 0.f;
          alpha2L[tid] = packh2(a0, a1);
        }
      }
      __syncthreads();
      {
        const unsigned* ec = encT2 + tid*27;
        float s = 0.f;
        #pragma unroll 5
        for (int p2 = 0; p2 < 25; p2++)
          s = fdot2f(ash2(ec[p2]), ash2(alpha2L[p2]), s);
        __hip_atomic_fetch_add(&p.xG[b*1024 + 512 + tid], gateL[tid]*s,
                               __ATOMIC_RELAXED, __HIP_MEMORY_SCOPE_AGENT);
      }
    }
    treebar(p.tb, blk, ++ep);   // B2

    // ======== P3: gates GEMM (K-split waves, acc[8] batches) + LSTM ========
    {
      for (int idx = tid; idx < 3072; idx += NTHR){
        int bb2 = idx & 7, k4 = idx >> 3;
        int b8 = bt*8 + bb2, k = 4*k4;
        float2 v0, v1;
        if (k < 1024){
          v0 = ldg2_c(&p.xG[b8*1024 + k]);
          v1 = ldg2_c(&p.xG[b8*1024 + k + 2]);
        } else {
          v0 = ldg2_c(&hR[b8*512 + (k - 1024)]);
          v1 = ldg2_c(&hR[b8*512 + (k - 1022)]);
        }
        uint2 u; u.x = packh2(v0.x, v0.y); u.y = packh2(v1.x, v1.y);
        xT2[idx] = u;                      // xT2[k4*8+bb]
      }
      __syncthreads();
      const int c = ct*64 + lane;
      const uint2* wg = (const uint2*)p.wG2;
      float acc[8];
      #pragma unroll
      for (int i = 0; i < 8; i++) acc[i] = 0.f;
      const int k40 = wave*48;
      #pragma unroll 4
      for (int k4 = k40; k4 < k40 + 48; k4++){
        uint2 w = wg[k4*2048 + c];
        uint4 x0 = xT4[k4*4+0], x1 = xT4[k4*4+1];
        uint4 x2 = xT4[k4*4+2], x3 = xT4[k4*4+3];
        ACC2(acc[0],acc[1],x0); ACC2(acc[2],acc[3],x1);
        ACC2(acc[4],acc[5],x2); ACC2(acc[6],acc[7],x3);
      }
      #pragma unroll
      for (int bb2 = 0; bb2 < 8; bb2++) redW[wave*512 + bb2*64 + lane] = acc[bb2];
      __syncthreads();
      {
        int bb2 = tid >> 6, l = tid & 63;
        float s = 0.f;
        #pragma unroll
        for (int w8 = 0; w8 < 8; w8++) s += redW[w8*512 + bb2*64 + l];
        gLs[bb2*64 + l] = s;
      }
      __syncthreads();
      if (tid < 128){
        int jj = tid >> 3, bb2 = tid & 7;
        int b8 = bt*8 + bb2, jg = ct*16 + jj;
        float g0 = gLs[bb2*64 + jj*4+0] + p.bih[jg]        + p.bhh[jg];
        float g1 = gLs[bb2*64 + jj*4+1] + p.bih[512 + jg]  + p.bhh[512 + jg];
        float g2 = gLs[bb2*64 + jj*4+2] + p.bih[1024 + jg] + p.bhh[1024 + jg];
        float g3 = gLs[bb2*64 + jj*4+3] + p.bih[1536 + jg] + p.bhh[1536 + jg];
        float i_s = sigf(g0), f_s = sigf(g1), g_t = tanhf_(g2), o_s = sigf(g3);
        float c_old = cL[jj*8 + bb2];
        float c_new = f_s*c_old + i_s*g_t;
        float h_new = o_s*tanhf_(c_new);
        bool m = t < p.dec_len[b8];
        float h_old = ldg_c(&hR[b8*512 + jg]);
        cL[jj*8 + bb2] = m ? c_new : c_old;
        stg_c(&p.hnG[b8*512 + jg], h_new);
        stg_c(&hW[b8*512 + jg], m ? h_new : h_old);
      }
    }
    treebar(p.tb, blk, ++ep);   // B0 (h(t+1), hn(t) published)
  }

  // ---- final preds for t = T-1 ----
  if (ct >= 16){
    for (int idx = tid; idx < 1024; idx += NTHR){
      int bb2 = idx & 7, k4 = idx >> 3;
      const float* src = &p.hnG[(bt*8 + bb2)*512 + 4*k4];
      float2 v0 = ldg2_c(src), v1 = ldg2_c(src + 2);
      uint2 u; u.x = packh2(v0.x, v0.y); u.y = packh2(v1.x, v1.y);
      xT2[idx] = u;
    }
    __syncthreads();
    const int vv = 1024 + (ct-16)*64 + lane;
    const uint2* wa = (const uint2*)p.wA2;
    float acc[8];
    #pragma unroll
    for (int i = 0; i < 8; i++) acc[i] = 0.f;
    const int k40 = wave*16;
    #pragma unroll 4
    for (int k4 = k40; k4 < k40 + 16; k4++){
      uint2 w = wa[k4*2048 + vv];
      uint4 x0 = xT4[k4*4+0], x1 = xT4[k4*4+1];
      uint4 x2 = xT4[k4*4+2], x3 = xT4[k4*4+3];
      ACC2(acc[0],acc[1],x0); ACC2(acc[2],acc[3],x1);
      ACC2(acc[4],acc[5],x2); ACC2(acc[6],acc[7],x3);
    }
    #pragma unroll
    for (int bb2 = 0; bb2 < 8; bb2++) redW[wave*512 + bb2*64 + lane] = acc[bb2];
    __syncthreads();
    {
      int bb2 = tid >> 6, l = tid & 63;
      int v2 = (ct-16)*64 + l;
      if (v2 < 1000){
        float s = 0.f;
        #pragma unroll
        for (int w8 = 0; w8 < 8; w8++) s += redW[w8*512 + bb2*64 + l];
        int b8 = bt*8 + bb2;
        bool mm = (T_-1) < p.dec_len[b8];
        p.out[OUT_PRED + ((size_t)b8*T_ + (T_-1))*V_ + v2] = mm ? (s + p.fcb[v2]) : 0.f;
      }
    }
  }
}

extern "C" void kernel_launch(void* const* d_in, const int* in_sizes, int n_in,
                              void* d_out, int out_size, void* d_ws, size_t ws_size,
                              hipStream_t stream){
  (void)in_sizes; (void)n_in; (void)out_size; (void)ws_size;
  KP p;
  p.enc  = (const float*)d_in[0];
  p.caps = (const int*)  d_in[1];
  p.clen = (const int*)  d_in[2];
  p.emb  = (const float*)d_in[3];
  p.eaw  = (const float*)d_in[4];  p.eab = (const float*)d_in[5];
  p.daw  = (const float*)d_in[6];  p.dab = (const float*)d_in[7];
  p.faw  = (const float*)d_in[8];  p.fab = (const float*)d_in[9];
  p.wih  = (const float*)d_in[10]; p.bih = (const float*)d_in[11];
  p.whh  = (const float*)d_in[12]; p.bhh = (const float*)d_in[13];
  p.ihw  = (const float*)d_in[14]; p.ihb = (const float*)d_in[15];
  p.icw  = (const float*)d_in[16]; p.icb = (const float*)d_in[17];
  p.fbw  = (const float*)d_in[18]; p.fbb = (const float*)d_in[19];
  p.fcw  = (const float*)d_in[20]; p.fcb = (const float*)d_in[21];
  p.out  = (float*)d_out;

  char* ws = (char*)d_ws;
  size_t off = 0;
  p.bar = (int*)(ws + off); off += 1024;    // fenced pre-barrier
  p.tb  = (int*)(ws + off); off += 1024;    // monotonic loop barrier
  p.sy  = (int*)(ws + off); off += 64*16*4; // per-b group counters
  size_t zero_bytes = off;
  p.sort_ind = (int*)(ws + off); off += 64*4;
  p.dec_len  = (int*)(ws + off); off += 64*4;
  off = (off + 255) & ~(size_t)255;
  p.mnT   = (float*)(ws + off); off += (size_t)B_*512*4;
  p.hA    = (float*)(ws + off); off += (size_t)B_*512*4;
  p.hB    = (float*)(ws + off); off += (size_t)B_*512*4;
  p.hnG   = (float*)(ws + off); off += (size_t)B_*512*4;
  p.a2G   = (float*)(ws + off); off += (size_t)B_*512*4;
  p.gateG = (float*)(ws + off); off += (size_t)B_*512*4;
  p.xG    = (float*)(ws + off); off += (size_t)B_*1024*4;
  p.eG    = (float*)(ws + off); off += (size_t)B_*256*4;
  p.att1  = (float*)(ws + off); off += (size_t)B_*P_*A_*4;
  p.wA2   = (unsigned*)(ws + off); off += (size_t)256*2048*4;
  p.wG2   = (unsigned*)(ws + off); off += (size_t)768*2048*4;

  hipMemsetAsync(ws, 0, zero_bytes, stream);

  void* args[] = { (void*)&p };
  hipLaunchCooperativeKernel((const void*)dec_kernel,
                             dim3(NBLK), dim3(NTHR), args, 0, stream);
}

// Round 2
// 6575.124 us; speedup vs baseline: 1.9316x; 1.0852x over previous
//
#include <hip/hip_runtime.h>
#include <cstdint>
#include <cstddef>

#define NBLK 256
#define NTHR 512
#define B_ 64
#define P_ 196
#define E_ 512
#define A_ 512
#define D_ 512
#define M_ 512
#define V_ 1000
#define L_ 257
#define T_ 256

#define OUT_PRED  0
#define OUT_CAPS  (B_*T_*V_)                 /* 16,384,000 */
#define OUT_ALPHA (OUT_CAPS + B_*L_)         /* 16,400,448 */
#define OUT_SORT  (OUT_ALPHA + B_*T_*P_)     /* 19,611,712 */

typedef _Float16 h2 __attribute__((ext_vector_type(2)));

struct KP {
  const float* enc; const int* caps; const int* clen;
  const float* emb;
  const float* eaw; const float* eab;
  const float* daw; const float* dab;
  const float* faw; const float* fab;
  const float* wih; const float* bih;
  const float* whh; const float* bhh;
  const float* ihw; const float* ihb;
  const float* icw; const float* icb;
  const float* fbw; const float* fbb;
  const float* fcw; const float* fcb;
  float* out;
  int* bar; int* flb; int* gf;
  int* sort_ind; int* dec_len;
  float* mnT; float* hA; float* hB; float* hnG;
  float* a2G; float* gateG; float* xG; float* eG; float* att1;
  unsigned* wA2; unsigned* wG2;
};

__device__ __forceinline__ float sigf(float x){ return 1.f/(1.f+__expf(-x)); }
__device__ __forceinline__ float tanhf_(float x){
  float ax = fabsf(x);
  float e = __expf(-2.f*ax);
  float r = (1.f-e)/(1.f+e);
  return x < 0.f ? -r : r;
}
__device__ __forceinline__ unsigned short f2bf(float x){
  unsigned u = __float_as_uint(x);
  unsigned r = (u + 0x7fffu + ((u >> 16) & 1u)) >> 16;   // RNE
  return (unsigned short)r;
}
__device__ __forceinline__ float fdot2f(h2 a, h2 b, float c){
#if __has_builtin(__builtin_amdgcn_fdot2)
  return __builtin_amdgcn_fdot2(a, b, c, false);
#else
  return c + (float)a.x*(float)b.x + (float)a.y*(float)b.y;
#endif
}
__device__ __forceinline__ unsigned packh2(float a, float b){
  h2 v; v.x = (_Float16)a; v.y = (_Float16)b;
  return __builtin_bit_cast(unsigned, v);
}
__device__ __forceinline__ h2 ash2(unsigned u){ return __builtin_bit_cast(h2, u); }

#define LD_A(p)     __hip_atomic_load((p), __ATOMIC_RELAXED, __HIP_MEMORY_SCOPE_AGENT)
#define ST_A(p,v)   __hip_atomic_store((p),(v), __ATOMIC_RELAXED, __HIP_MEMORY_SCOPE_AGENT)
#define ST_REL(p,v) __hip_atomic_store((p),(v), __ATOMIC_RELEASE, __HIP_MEMORY_SCOPE_AGENT)
#define FAA(p)      __hip_atomic_fetch_add((p),1, __ATOMIC_RELAXED, __HIP_MEMORY_SCOPE_AGENT)
__device__ __forceinline__ float ldg_c(const float* p){
  return __hip_atomic_load(p, __ATOMIC_RELAXED, __HIP_MEMORY_SCOPE_AGENT);
}
__device__ __forceinline__ float2 ldg2_c(const float* p){
  unsigned long long u = __hip_atomic_load((const unsigned long long*)p,
                       __ATOMIC_RELAXED, __HIP_MEMORY_SCOPE_AGENT);
  return __builtin_bit_cast(float2, u);
}
__device__ __forceinline__ void stg_c(float* p, float v){
  __hip_atomic_store(p, v, __ATOMIC_RELAXED, __HIP_MEMORY_SCOPE_AGENT);
}

// Fenced grid barrier -- pre-phase only (global, 3 uses).
__device__ __forceinline__ void gridbar(int* bar, int blk){
  __syncthreads();
  if (threadIdx.x == 0){
    __builtin_amdgcn_fence(__ATOMIC_RELEASE, "agent");
    int s = LD_A(&bar[144]);
    int* leaf = &bar[(blk & 7)*16];
    if (FAA(leaf) == 31){
      ST_A(leaf, 0);
      if (FAA(&bar[128]) == 7){
        ST_A(&bar[128], 0);
        ST_REL(&bar[144], s+1);
      }
    }
    while (LD_A(&bar[144]) == s) __builtin_amdgcn_s_sleep(2);
    __builtin_amdgcn_fence(__ATOMIC_ACQUIRE, "agent");
  }
  __syncthreads();
}

// Octet-scoped flat flag barrier for the time loop.
// All time-loop data flow is closed within a 32-block octet (blocks
// [32*O, 32*O+32) own batches [8*O, 8*O+8) in every phase), so the grid
// barrier shrinks to 32 blocks. Flag protocol: each block release-stores
// its monotonic epoch to its OWN flag (no atomic RMW serialization; the
// preceding __syncthreads drains vmcnt so all sc-scoped stores are
// LLC-visible first -- same mechanism the old treebar validated), then 32
// lanes poll the 32 flags (2 cache lines, coalesced). Monotonic epochs ->
// no reset races.
__device__ __forceinline__ void octbar(int* fl, int O, int r, int ep){
  __syncthreads();
  if (threadIdx.x == 0) ST_A(&fl[O*64 + r], ep);
  if (threadIdx.x < 32){
    while (LD_A(&fl[O*64 + (int)threadIdx.x]) < ep) __builtin_amdgcn_s_sleep(2);
  }
  asm volatile("" ::: "memory");
  __syncthreads();
}

// One weight-uint2 (4 k-elems) x 2 batches (uint4 from transposed x in LDS).
#define ACC2(a0,a1,xx) \
  a0 = fdot2f(ash2(w.x), ash2(xx.x), a0); \
  a0 = fdot2f(ash2(w.y), ash2(xx.y), a0); \
  a1 = fdot2f(ash2(w.x), ash2(xx.z), a1); \
  a1 = fdot2f(ash2(w.y), ash2(xx.w), a1);

// LDS map (147.5 KB):
//   [0,      50176) att1L  bf16[49][512]  resident (P2 identity: b=blk>>2,q=blk&3)
//   [50176, 105472) encT2  h2[512][27]    resident
//   [105472,107520) fwL    f32[512]       resident
//   [107520,108032) cL     f32[16][8]     persistent LSTM cell slice (P3 identity)
//   [108032,   ...) SCRATCH (phase-local, aliased):
//     GEMM phases: xT2 uint2[k4][8bb]  (P1: 8KB, P3: 24KB) at +0
//                  redW f32[8w][8bb][64c] (16KB) at +24576
//                  gLs  f32[512] (2KB) at +40960 (P3 only)
//     P2: a2L[512] gateL[512] eL[256] alphaL[256] alpha2L[32] at +0
// Pre1 tile GEMM aliases [0, 76032) -- dead before residents are written.
//
// K-split GEMM scheme: the 8 waves of a block split K 8 ways; each thread
// holds acc[8] (one per batch of its bt-octet), reads each weight uint2
// ONCE per block, broadcasts x from transposed LDS (uniform-address
// ds_read = free), then reduces wave partials through redW.
__global__ __launch_bounds__(NTHR, 2) void dec_kernel(KP p){
  __shared__ __align__(16) char smem_raw[151040];
  unsigned short* att1L = (unsigned short*)smem_raw;
  unsigned* encT2  = (unsigned*)(smem_raw + 50176);
  float* fwL       = (float*)(smem_raw + 105472);
  float* cL        = (float*)(smem_raw + 107520);
  char* SCR        = smem_raw + 108032;
  uint2* xT2       = (uint2*)SCR;                    // transposed packed x
  const uint4* xT4 = (const uint4*)SCR;              // same buffer, b128 view
  float* redW      = (float*)(SCR + 24576);          // wave partials 16KB
  float* gLs       = (float*)(SCR + 40960);          // P3 gate sums 2KB
  float* a2L       = (float*)SCR;                    // P2
  float* gateL     = (float*)(SCR + 2048);
  float* eL        = (float*)(SCR + 4096);
  float* alphaL    = (float*)(SCR + 5120);
  unsigned* alpha2L= (unsigned*)(SCR + 6144);

  const int blk  = blockIdx.x;
  const int tid  = threadIdx.x;
  const int lane = tid & 63;
  const int wave = tid >> 6;
  // P2 identity
  const int b    = blk >> 2;
  const int q    = blk & 3;
  // P1/P3 identity: column-tile x batch-octet
  const int ct   = blk & 31;          // 0..31  (also octet rank r)
  const int bt   = blk >> 5;          // 0..7   (also octet id O)

  // ---------------- Pre0: stable descending argsort + caps gather ----------------
  if (blk == 0){
    if (tid < B_){
      int lb = p.clen[tid];
      int rank = 0;
      for (int j = 0; j < B_; j++){
        int lj = p.clen[j];
        rank += (lj > lb) || (lj == lb && j < tid);
      }
      p.sort_ind[rank] = tid;
      p.dec_len[rank]  = lb - 1;
      p.out[OUT_SORT + rank] = (float)tid;
    }
    __syncthreads();
    for (int idx = tid; idx < B_*L_; idx += NTHR){
      int bb = idx / L_;
      int l = idx - bb*L_;
      int sbv = p.sort_ind[bb];
      p.out[OUT_CAPS + idx] = (float)p.caps[sbv*L_ + l];
    }
  }
  gridbar(p.bar, blk);

  const int sb  = p.sort_ind[b];
  const int dlb = p.dec_len[b];

  // ---------------- Pre1: att1 = enc_s @ enc_att_w^T + b (196 tiles) + mean (64) ----------------
  for (int task = blk; task < 260; task += NBLK){
    if (task < 196){
      const int r0 = task*64;
      float* wL = (float*)smem_raw;             // [512][33]
      float* eLt = (float*)smem_raw + 512*33;   // [64][33]
      const int tx = tid & 31, ty = tid >> 5;   // ty<16
      float acc[4][16];
      #pragma unroll
      for (int i=0;i<4;i++)
        #pragma unroll
        for (int j=0;j<16;j++) acc[i][j] = 0.f;
      for (int k0 = 0; k0 < 512; k0 += 32){
        __syncthreads();
        for (int i = tid; i < 512*32; i += NTHR){
          int a = i >> 5, kk = i & 31;
          wL[a*33 + kk] = p.eaw[a*512 + k0 + kk];
        }
        for (int i = tid; i < 64*32; i += NTHR){
          int rl = i >> 5, kk = i & 31;
          int r = r0 + rl;
          int bb = r / 196;
          int pp = r - bb*196;
          int sbv = p.sort_ind[bb];
          eLt[rl*33 + kk] = p.enc[((size_t)sbv*196 + pp)*512 + k0 + kk];
        }
        __syncthreads();
        for (int kk = 0; kk < 32; kk++){
          float ev[4];
          #pragma unroll
          for (int ii=0;ii<4;ii++) ev[ii] = eLt[(ty*4+ii)*33 + kk];
          #pragma unroll
          for (int jj=0;jj<16;jj++){
            float wv = wL[(tx + 32*jj)*33 + kk];
            #pragma unroll
            for (int ii=0;ii<4;ii++) acc[ii][jj] = fmaf(ev[ii], wv, acc[ii][jj]);
          }
        }
      }
      #pragma unroll
      for (int jj=0;jj<16;jj++){
        int a = tx + 32*jj;
        float bbv = p.eab[a];
        #pragma unroll
        for (int ii=0;ii<4;ii++){
          int r = r0 + ty*4 + ii;
          p.att1[(size_t)r*512 + a] = acc[ii][jj] + bbv;
        }
      }
      __syncthreads();
    } else {
      int bb = task - 196;
      int sbv = p.sort_ind[bb];
      const float* eb = p.enc + (size_t)sbv*P_*E_;
      for (int e = tid; e < E_; e += NTHR){
        float s = 0.f;
        for (int pp = 0; pp < P_; pp++) s += eb[pp*E_ + e];
        p.mnT[bb*512 + e] = s * (1.f/196.f);
      }
    }
  }
  gridbar(p.bar, blk);

  // ---------------- Pre2: residents + f16 weight tables + h0/c0 ----------------
  // (a) P2 residents
  for (int idx = tid; idx < 49*512; idx += NTHR){
    int pp = idx >> 9, a = idx & 511;
    att1L[idx] = f2bf(p.att1[((size_t)(b*196 + q*49 + pp))*512 + a]);
  }
  for (int i = tid; i < 512*25; i += NTHR){
    int p2 = i >> 9, e = i & 511;
    int pr0 = q*49 + 2*p2;
    float e0 = p.enc[((size_t)sb*196 + pr0)*512 + e];
    float e1 = (2*p2+1 < 49) ? p.enc[((size_t)sb*196 + pr0 + 1)*512 + e] : 0.f;
    encT2[e*27 + p2] = packh2(e0, e1);
  }
  fwL[tid] = p.faw[tid];
  // (b) wA2: k2-slice = blk; vcols: 0-511 daw, 512-1023 fbw, 1024-2023 fcw
  {
    int k2 = blk, k = 2*k2;
    for (int vc = tid; vc < 2048; vc += NTHR){
      float w0 = 0.f, w1 = 0.f;
      if (vc < 512){ const float* r = p.daw + (size_t)vc*512 + k; w0 = r[0]; w1 = r[1]; }
      else if (vc < 1024){ const float* r = p.fbw + (size_t)(vc-512)*512 + k; w0 = r[0]; w1 = r[1]; }
      else if (vc < 2024){ const float* r = p.fcw + (size_t)(vc-1024)*512 + k; w0 = r[0]; w1 = r[1]; }
      p.wA2[((size_t)(k2>>1)*2048 + vc)*2 + (k2&1)] = packh2(w0, w1);
    }
  }
  // (c) wG2: k2-slices blk*3..+2; col c = j*4+g -> row g*512+j
  for (int s = 0; s < 3; s++){
    int k2 = blk*3 + s, k = 2*k2;
    for (int c = tid; c < 2048; c += NTHR){
      int j = c >> 2, g = c & 3, r = g*512 + j;
      float w0, w1;
      if (k2 < 512){ const float* rr = p.wih + (size_t)r*1024 + k; w0 = rr[0]; w1 = rr[1]; }
      else         { const float* rr = p.whh + (size_t)r*512 + (k-1024); w0 = rr[0]; w1 = rr[1]; }
      p.wG2[((size_t)(k2>>1)*2048 + c)*2 + (k2&1)] = packh2(w0, w1);
    }
  }
  // (d) h0/c0 for P3 slice (ct: 16 j's, bt: 8 b's)
  if (tid < 128){
    int jj = tid >> 3, bb2 = tid & 7;
    int b8 = bt*8 + bb2, jg = ct*16 + jj;
    const float* mrow = p.mnT + b8*512;
    const float* hw = p.ihw + (size_t)jg*512;
    const float* cw = p.icw + (size_t)jg*512;
    float ah = 0.f, ac = 0.f;
    for (int k = 0; k < 512; k++){ ah = fmaf(hw[k], mrow[k], ah); ac = fmaf(cw[k], mrow[k], ac); }
    stg_c(&p.hA[b8*512 + jg], ah + p.ihb[jg]);
    cL[jj*8 + bb2] = ac + p.icb[jg];
  }
  gridbar(p.bar, blk);

  const float fab0 = p.fab[0];
  int ep = 0;

  // ---------------- time loop: 3 octet flag barriers + 1 flag group sync ----------------
  for (int t = 0; t < T_; t++){
    const float* hR = (t & 1) ? p.hB : p.hA;   // h(t)
    float*       hW = (t & 1) ? p.hA : p.hB;   // h(t+1)

    // ======== P1: a2+gate (ct<16) | preds(t-1) (ct>=16) ========
    // K-split: wave w does k4 in [w*16, w*16+16); acc[8] = 8 batches.
    if (ct < 16){
      for (int idx = tid; idx < 1024; idx += NTHR){
        int bb2 = idx & 7, k4 = idx >> 3;
        const float* src = &hR[(bt*8 + bb2)*512 + 4*k4];
        float2 v0 = ldg2_c(src), v1 = ldg2_c(src + 2);
        uint2 u; u.x = packh2(v0.x, v0.y); u.y = packh2(v1.x, v1.y);
        xT2[idx] = u;                      // xT2[k4*8+bb]
      }
      __syncthreads();
      const int vc = ct*64 + lane;
      const uint2* wa = (const uint2*)p.wA2;
      float acc[8];
      #pragma unroll
      for (int i = 0; i < 8; i++) acc[i] = 0.f;
      const int k40 = wave*16;
      #pragma unroll 4
      for (int k4 = k40; k4 < k40 + 16; k4++){
        uint2 w = wa[k4*2048 + vc];
        uint4 x0 = xT4[k4*4+0], x1 = xT4[k4*4+1];
        uint4 x2 = xT4[k4*4+2], x3 = xT4[k4*4+3];
        ACC2(acc[0],acc[1],x0); ACC2(acc[2],acc[3],x1);
        ACC2(acc[4],acc[5],x2); ACC2(acc[6],acc[7],x3);
      }
      #pragma unroll
      for (int bb2 = 0; bb2 < 8; bb2++) redW[wave*512 + bb2*64 + lane] = acc[bb2];
      __syncthreads();
      {
        int bb2 = tid >> 6, l = tid & 63;
        float s = 0.f;
        #pragma unroll
        for (int w8 = 0; w8 < 8; w8++) s += redW[w8*512 + bb2*64 + l];
        int b8 = bt*8 + bb2, vcl = ct*64 + l;
        if (vcl < 512) stg_c(&p.a2G[b8*512 + vcl], s + p.dab[vcl]);
        else           stg_c(&p.gateG[b8*512 + (vcl-512)], sigf(s + p.fbb[vcl-512]));
      }
    } else if (t > 0){
      for (int idx = tid; idx < 1024; idx += NTHR){
        int bb2 = idx & 7, k4 = idx >> 3;
        const float* src = &p.hnG[(bt*8 + bb2)*512 + 4*k4];
        float2 v0 = ldg2_c(src), v1 = ldg2_c(src + 2);
        uint2 u; u.x = packh2(v0.x, v0.y); u.y = packh2(v1.x, v1.y);
        xT2[idx] = u;
      }
      __syncthreads();
      const int vv = 1024 + (ct-16)*64 + lane;   // fcw columns (zeros >= 2024)
      const uint2* wa = (const uint2*)p.wA2;
      float acc[8];
      #pragma unroll
      for (int i = 0; i < 8; i++) acc[i] = 0.f;
      const int k40 = wave*16;
      #pragma unroll 4
      for (int k4 = k40; k4 < k40 + 16; k4++){
        uint2 w = wa[k4*2048 + vv];
        uint4 x0 = xT4[k4*4+0], x1 = xT4[k4*4+1];
        uint4 x2 = xT4[k4*4+2], x3 = xT4[k4*4+3];
        ACC2(acc[0],acc[1],x0); ACC2(acc[2],acc[3],x1);
        ACC2(acc[4],acc[5],x2); ACC2(acc[6],acc[7],x3);
      }
      #pragma unroll
      for (int bb2 = 0; bb2 < 8; bb2++) redW[wave*512 + bb2*64 + lane] = acc[bb2];
      __syncthreads();
      {
        int bb2 = tid >> 6, l = tid & 63;
        int v2 = (ct-16)*64 + l;
        if (v2 < 1000){
          float s = 0.f;
          #pragma unroll
          for (int w8 = 0; w8 < 8; w8++) s += redW[w8*512 + bb2*64 + l];
          int b8 = bt*8 + bb2;
          bool mm = (t-1) < p.dec_len[b8];
          p.out[OUT_PRED + ((size_t)b8*T_ + (t-1))*V_ + v2] = mm ? (s + p.fcb[v2]) : 0.f;
        }
      }
    }
    octbar(p.flb, bt, ct, ++ep);   // B1 (octet-scoped)

    // ======== P2: attention (group of 4 blocks per b) ========
    {
      a2L[tid]   = ldg_c(&p.a2G[b*512 + tid]);
      gateL[tid] = ldg_c(&p.gateG[b*512 + tid]);
      if (tid < 128) stg_c(&p.xG[b*1024 + 512 + q*128 + tid], 0.f);
      {
        int cap = p.caps[sb*L_ + t];
        if (tid < 128)
          stg_c(&p.xG[b*1024 + q*128 + tid], p.emb[(size_t)cap*M_ + q*128 + tid]);
      }
      __syncthreads();
      // e for own 49 rows from bf16 att1L
      {
        float4 aA = ((float4*)a2L)[lane*2], aB = ((float4*)a2L)[lane*2+1];
        float4 fA = ((float4*)fwL)[lane*2], fB = ((float4*)fwL)[lane*2+1];
        for (int pp = wave; pp < 49; pp += 8){
          uint4 raw = ((const uint4*)att1L)[pp*64 + lane];
          float s =
            fmaxf(__uint_as_float(raw.x << 16)        + aA.x, 0.f)*fA.x +
            fmaxf(__uint_as_float(raw.x & 0xffff0000u)+ aA.y, 0.f)*fA.y +
            fmaxf(__uint_as_float(raw.y << 16)        + aA.z, 0.f)*fA.z +
            fmaxf(__uint_as_float(raw.y & 0xffff0000u)+ aA.w, 0.f)*fA.w +
            fmaxf(__uint_as_float(raw.z << 16)        + aB.x, 0.f)*fB.x +
            fmaxf(__uint_as_float(raw.z & 0xffff0000u)+ aB.y, 0.f)*fB.y +
            fmaxf(__uint_as_float(raw.w << 16)        + aB.z, 0.f)*fB.z +
            fmaxf(__uint_as_float(raw.w & 0xffff0000u)+ aB.w, 0.f)*fB.w;
          #pragma unroll
          for (int o = 32; o > 0; o >>= 1) s += __shfl_down(s, o);
          if (lane == 0) stg_c(&p.eG[b*256 + q*49 + pp], s + fab0);
        }
      }
      // group sync: e complete (also orders xG zero vs atomicAdd below).
      // Flag protocol: each q stores epoch t+1 to its own flag; 4 lanes poll.
      __syncthreads();
      if (tid == 0) ST_A(&p.gf[b*16 + q], t+1);
      if (tid < 4){
        while (LD_A(&p.gf[b*16 + tid]) < t+1) __builtin_amdgcn_s_sleep(1);
      }
      asm volatile("" ::: "memory");
      __syncthreads();
      if (tid < 196) eL[tid] = ldg_c(&p.eG[b*256 + tid]);
      __syncthreads();
      if (wave == 0){
        float mx = -1e30f;
        for (int i = lane; i < P_; i += 64) mx = fmaxf(mx, eL[i]);
        #pragma unroll
        for (int o = 32; o > 0; o >>= 1) mx = fmaxf(mx, __shfl_xor(mx, o));
        float sum = 0.f;
        for (int i = lane; i < P_; i += 64){
          float ex = __expf(eL[i] - mx);
          alphaL[i] = ex;
          sum += ex;
        }
        #pragma unroll
        for (int o = 32; o > 0; o >>= 1) sum += __shfl_xor(sum, o);
        float inv = 1.f / sum;
        for (int i = lane; i < P_; i += 64) alphaL[i] *= inv;
      }
      __syncthreads();
      {
        bool mb = t < dlb;
        if (tid < 49)
          p.out[OUT_ALPHA + ((size_t)b*T_ + t)*P_ + q*49 + tid] = mb ? alphaL[q*49 + tid] : 0.f;
        if (tid < 25){
          float a0 = alphaL[q*49 + 2*tid];
          float a1 = (2*tid+1 < 49) ? alphaL[q*49 + 2*tid + 1] : 0.f;
          alpha2L[tid] = packh2(a0, a1);
        }
      }
      __syncthreads();
      {
        const unsigned* ec = encT2 + tid*27;
        float s = 0.f;
        #pragma unroll 5
        for (int p2 = 0; p2 < 25; p2++)
          s = fdot2f(ash2(ec[p2]), ash2(alpha2L[p2]), s);
        __hip_atomic_fetch_add(&p.xG[b*1024 + 512 + tid], gateL[tid]*s,
                               __ATOMIC_RELAXED, __HIP_MEMORY_SCOPE_AGENT);
      }
    }
    octbar(p.flb, bt, ct, ++ep);   // B2 (octet-scoped)

    // ======== P3: gates GEMM (K-split waves, acc[8] batches) + LSTM ========
    {
      for (int idx = tid; idx < 3072; idx += NTHR){
        int bb2 = idx & 7, k4 = idx >> 3;
        int b8 = bt*8 + bb2, k = 4*k4;
        float2 v0, v1;
        if (k < 1024){
          v0 = ldg2_c(&p.xG[b8*1024 + k]);
          v1 = ldg2_c(&p.xG[b8*1024 + k + 2]);
        } else {
          v0 = ldg2_c(&hR[b8*512 + (k - 1024)]);
          v1 = ldg2_c(&hR[b8*512 + (k - 1022)]);
        }
        uint2 u; u.x = packh2(v0.x, v0.y); u.y = packh2(v1.x, v1.y);
        xT2[idx] = u;                      // xT2[k4*8+bb]
      }
      __syncthreads();
      const int c = ct*64 + lane;
      const uint2* wg = (const uint2*)p.wG2;
      float acc[8];
      #pragma unroll
      for (int i = 0; i < 8; i++) acc[i] = 0.f;
      const int k40 = wave*48;
      #pragma unroll 4
      for (int k4 = k40; k4 < k40 + 48; k4++){
        uint2 w = wg[k4*2048 + c];
        uint4 x0 = xT4[k4*4+0], x1 = xT4[k4*4+1];
        uint4 x2 = xT4[k4*4+2], x3 = xT4[k4*4+3];
        ACC2(acc[0],acc[1],x0); ACC2(acc[2],acc[3],x1);
        ACC2(acc[4],acc[5],x2); ACC2(acc[6],acc[7],x3);
      }
      #pragma unroll
      for (int bb2 = 0; bb2 < 8; bb2++) redW[wave*512 + bb2*64 + lane] = acc[bb2];
      __syncthreads();
      {
        int bb2 = tid >> 6, l = tid & 63;
        float s = 0.f;
        #pragma unroll
        for (int w8 = 0; w8 < 8; w8++) s += redW[w8*512 + bb2*64 + l];
        gLs[bb2*64 + l] = s;
      }
      __syncthreads();
      if (tid < 128){
        int jj = tid >> 3, bb2 = tid & 7;
        int b8 = bt*8 + bb2, jg = ct*16 + jj;
        float g0 = gLs[bb2*64 + jj*4+0] + p.bih[jg]        + p.bhh[jg];
        float g1 = gLs[bb2*64 + jj*4+1] + p.bih[512 + jg]  + p.bhh[512 + jg];
        float g2 = gLs[bb2*64 + jj*4+2] + p.bih[1024 + jg] + p.bhh[1024 + jg];
        float g3 = gLs[bb2*64 + jj*4+3] + p.bih[1536 + jg] + p.bhh[1536 + jg];
        float i_s = sigf(g0), f_s = sigf(g1), g_t = tanhf_(g2), o_s = sigf(g3);
        float c_old = cL[jj*8 + bb2];
        float c_new = f_s*c_old + i_s*g_t;
        float h_new = o_s*tanhf_(c_new);
        bool m = t < p.dec_len[b8];
        float h_old = ldg_c(&hR[b8*512 + jg]);
        cL[jj*8 + bb2] = m ? c_new : c_old;
        stg_c(&p.hnG[b8*512 + jg], h_new);
        stg_c(&hW[b8*512 + jg], m ? h_new : h_old);
      }
    }
    octbar(p.flb, bt, ct, ++ep);   // B0 (h(t+1), hn(t) published; octet-scoped)
  }

  // ---- final preds for t = T-1 ----
  if (ct >= 16){
    for (int idx = tid; idx < 1024; idx += NTHR){
      int bb2 = idx & 7, k4 = idx >> 3;
      const float* src = &p.hnG[(bt*8 + bb2)*512 + 4*k4];
      float2 v0 = ldg2_c(src), v1 = ldg2_c(src + 2);
      uint2 u; u.x = packh2(v0.x, v0.y); u.y = packh2(v1.x, v1.y);
      xT2[idx] = u;
    }
    __syncthreads();
    const int vv = 1024 + (ct-16)*64 + lane;
    const uint2* wa = (const uint2*)p.wA2;
    float acc[8];
    #pragma unroll
    for (int i = 0; i < 8; i++) acc[i] = 0.f;
    const int k40 = wave*16;
    #pragma unroll 4
    for (int k4 = k40; k4 < k40 + 16; k4++){
      uint2 w = wa[k4*2048 + vv];
      uint4 x0 = xT4[k4*4+0], x1 = xT4[k4*4+1];
      uint4 x2 = xT4[k4*4+2], x3 = xT4[k4*4+3];
      ACC2(acc[0],acc[1],x0); ACC2(acc[2],acc[3],x1);
      ACC2(acc[4],acc[5],x2); ACC2(acc[6],acc[7],x3);
    }
    #pragma unroll
    for (int bb2 = 0; bb2 < 8; bb2++) redW[wave*512 + bb2*64 + lane] = acc[bb2];
    __syncthreads();
    {
      int bb2 = tid >> 6, l = tid & 63;
      int v2 = (ct-16)*64 + l;
      if (v2 < 1000){
        float s = 0.f;
        #pragma unroll
        for (int w8 = 0; w8 < 8; w8++) s += redW[w8*512 + bb2*64 + l];
        int b8 = bt*8 + bb2;
        bool mm = (T_-1) < p.dec_len[b8];
        p.out[OUT_PRED + ((size_t)b8*T_ + (T_-1))*V_ + v2] = mm ? (s + p.fcb[v2]) : 0.f;
      }
    }
  }
}

extern "C" void kernel_launch(void* const* d_in, const int* in_sizes, int n_in,
                              void* d_out, int out_size, void* d_ws, size_t ws_size,
                              hipStream_t stream){
  (void)in_sizes; (void)n_in; (void)out_size; (void)ws_size;
  KP p;
  p.enc  = (const float*)d_in[0];
  p.caps = (const int*)  d_in[1];
  p.clen = (const int*)  d_in[2];
  p.emb  = (const float*)d_in[3];
  p.eaw  = (const float*)d_in[4];  p.eab = (const float*)d_in[5];
  p.daw  = (const float*)d_in[6];  p.dab = (const float*)d_in[7];
  p.faw  = (const float*)d_in[8];  p.fab = (const float*)d_in[9];
  p.wih  = (const float*)d_in[10]; p.bih = (const float*)d_in[11];
  p.whh  = (const float*)d_in[12]; p.bhh = (const float*)d_in[13];
  p.ihw  = (const float*)d_in[14]; p.ihb = (const float*)d_in[15];
  p.icw  = (const float*)d_in[16]; p.icb = (const float*)d_in[17];
  p.fbw  = (const float*)d_in[18]; p.fbb = (const float*)d_in[19];
  p.fcw  = (const float*)d_in[20]; p.fcb = (const float*)d_in[21];
  p.out  = (float*)d_out;

  char* ws = (char*)d_ws;
  size_t off = 0;
  p.bar = (int*)(ws + off); off += 1024;     // fenced pre-barrier (global)
  p.flb = (int*)(ws + off); off += 8*64*4;   // octet flag barrier (8 octets x 64 ints)
  p.gf  = (int*)(ws + off); off += 64*16*4;  // per-b group flags (4 used per b)
  size_t zero_bytes = off;
  p.sort_ind = (int*)(ws + off); off += 64*4;
  p.dec_len  = (int*)(ws + off); off += 64*4;
  off = (off + 255) & ~(size_t)255;
  p.mnT   = (float*)(ws + off); off += (size_t)B_*512*4;
  p.hA    = (float*)(ws + off); off += (size_t)B_*512*4;
  p.hB    = (float*)(ws + off); off += (size_t)B_*512*4;
  p.hnG   = (float*)(ws + off); off += (size_t)B_*512*4;
  p.a2G   = (float*)(ws + off); off += (size_t)B_*512*4;
  p.gateG = (float*)(ws + off); off += (size_t)B_*512*4;
  p.xG    = (float*)(ws + off); off += (size_t)B_*1024*4;
  p.eG    = (float*)(ws + off); off += (size_t)B_*256*4;
  p.att1  = (float*)(ws + off); off += (size_t)B_*P_*A_*4;
  p.wA2   = (unsigned*)(ws + off); off += (size_t)256*2048*4;
  p.wG2   = (unsigned*)(ws + off); off += (size_t)768*2048*4;

  hipMemsetAsync(ws, 0, zero_bytes, stream);

  void* args[] = { (void*)&p };
  hipLaunchCooperativeKernel((const void*)dec_kernel,
                             dim3(NBLK), dim3(NTHR), args, 0, stream);
}

// Round 3
// 5634.249 us; speedup vs baseline: 2.2541x; 1.1670x over previous
//
#include <hip/hip_runtime.h>
#include <cstdint>
#include <cstddef>

#define NBLK 256
#define NTHR 512
#define B_ 64
#define P_ 196
#define E_ 512
#define A_ 512
#define D_ 512
#define M_ 512
#define V_ 1000
#define L_ 257
#define T_ 256

#define OUT_PRED  0
#define OUT_CAPS  (B_*T_*V_)                 /* 16,384,000 */
#define OUT_ALPHA (OUT_CAPS + B_*L_)         /* 16,400,448 */
#define OUT_SORT  (OUT_ALPHA + B_*T_*P_)     /* 19,611,712 */

typedef _Float16 h2 __attribute__((ext_vector_type(2)));
typedef _Float16 f16x8 __attribute__((ext_vector_type(8)));
typedef float f32x4 __attribute__((ext_vector_type(4)));

struct KP {
  const float* enc; const int* caps; const int* clen;
  const float* emb;
  const float* eaw; const float* eab;
  const float* daw; const float* dab;
  const float* faw; const float* fab;
  const float* wih; const float* bih;
  const float* whh; const float* bhh;
  const float* ihw; const float* ihb;
  const float* icw; const float* icb;
  const float* fbw; const float* fbb;
  const float* fcw; const float* fcb;
  float* out;
  int* bar; int* flb; int* gf;
  int* sort_ind; int* dec_len;
  float* mnT; float* hA; float* hB; float* hnG;
  float* a2G; float* gateG; float* aweQ; float* eG; float* att1;
  unsigned* wA2; unsigned* wG2;
};

__device__ __forceinline__ float sigf(float x){ return 1.f/(1.f+__expf(-x)); }
__device__ __forceinline__ float tanhf_(float x){
  float ax = fabsf(x);
  float e = __expf(-2.f*ax);
  float r = (1.f-e)/(1.f+e);
  return x < 0.f ? -r : r;
}
__device__ __forceinline__ unsigned short f2bf(float x){
  unsigned u = __float_as_uint(x);
  unsigned r = (u + 0x7fffu + ((u >> 16) & 1u)) >> 16;   // RNE
  return (unsigned short)r;
}
__device__ __forceinline__ float fdot2f(h2 a, h2 b, float c){
#if __has_builtin(__builtin_amdgcn_fdot2)
  return __builtin_amdgcn_fdot2(a, b, c, false);
#else
  return c + (float)a.x*(float)b.x + (float)a.y*(float)b.y;
#endif
}
__device__ __forceinline__ unsigned packh2(float a, float b){
  h2 v; v.x = (_Float16)a; v.y = (_Float16)b;
  return __builtin_bit_cast(unsigned, v);
}
__device__ __forceinline__ h2 ash2(unsigned u){ return __builtin_bit_cast(h2, u); }
__device__ __forceinline__ f16x8 asf8(uint4 u){ return __builtin_bit_cast(f16x8, u); }

#define LD_A(p)     __hip_atomic_load((p), __ATOMIC_RELAXED, __HIP_MEMORY_SCOPE_AGENT)
#define ST_A(p,v)   __hip_atomic_store((p),(v), __ATOMIC_RELAXED, __HIP_MEMORY_SCOPE_AGENT)
#define ST_REL(p,v) __hip_atomic_store((p),(v), __ATOMIC_RELEASE, __HIP_MEMORY_SCOPE_AGENT)
#define FAA(p)      __hip_atomic_fetch_add((p),1, __ATOMIC_RELAXED, __HIP_MEMORY_SCOPE_AGENT)
__device__ __forceinline__ float ldg_c(const float* p){
  return __hip_atomic_load(p, __ATOMIC_RELAXED, __HIP_MEMORY_SCOPE_AGENT);
}
__device__ __forceinline__ float2 ldg2_c(const float* p){
  unsigned long long u = __hip_atomic_load((const unsigned long long*)p,
                       __ATOMIC_RELAXED, __HIP_MEMORY_SCOPE_AGENT);
  return __builtin_bit_cast(float2, u);
}
__device__ __forceinline__ void stg_c(float* p, float v){
  __hip_atomic_store(p, v, __ATOMIC_RELAXED, __HIP_MEMORY_SCOPE_AGENT);
}

// Fenced grid barrier -- pre-phase only (global, 3 uses).
__device__ __forceinline__ void gridbar(int* bar, int blk){
  __syncthreads();
  if (threadIdx.x == 0){
    __builtin_amdgcn_fence(__ATOMIC_RELEASE, "agent");
    int s = LD_A(&bar[144]);
    int* leaf = &bar[(blk & 7)*16];
    if (FAA(leaf) == 31){
      ST_A(leaf, 0);
      if (FAA(&bar[128]) == 7){
        ST_A(&bar[128], 0);
        ST_REL(&bar[144], s+1);
      }
    }
    while (LD_A(&bar[144]) == s) __builtin_amdgcn_s_sleep(2);
    __builtin_amdgcn_fence(__ATOMIC_ACQUIRE, "agent");
  }
  __syncthreads();
}

// Octet-scoped flat flag barrier for the time loop (see R1 notes): each
// block release-stores its monotonic epoch to its own flag; 32 lanes poll.
__device__ __forceinline__ void octbar(int* fl, int O, int r, int ep){
  __syncthreads();
  if (threadIdx.x == 0) ST_A(&fl[O*64 + r], ep);
  if (threadIdx.x < 32){
    while (LD_A(&fl[O*64 + (int)threadIdx.x]) < ep) __builtin_amdgcn_s_sleep(2);
  }
  asm volatile("" ::: "memory");
  __syncthreads();
}

// ---------------- MFMA K-split GEMV ----------------
// Per block: D[64 cols][8 batches] via 4 M-tiles of mfma_f32_16x16x32_f16.
// A (M=16 cols x K=32) = weights, PREPACKED in fragment layout in ws:
//   uint4 idx = ((ct*4+mt)*KST + ksg)*64 + lane; elems e: k = ksg*32+(l>>4)*8+e,
//   col = ct*64+mt*16+(l&15).  One coalesced dwordx4 per lane per tile.
// B (K=32 x N=16 batches) = x from LDS, chunk-major f16 [K/8][8], lane reads
//   chunk (ksg*4+(l>>4)) row (l&7) -- one ds_read_b128, 4-way bank (optimal).
//   Lanes with (l&15)>=8 read duplicate rows; their D columns are ignored.
// K is split 8 ways across waves (weights read ONCE per block), partials
// reduced through redW (f32[8w][512]); slot = c_local*8 + j = reduce tid.
template<int KSW>
__device__ __forceinline__ void gemv_mfma(const uint4* __restrict__ wct,
                                          const uint4* __restrict__ x4,
                                          float* redW, int lane, int wave){
  constexpr int KST = KSW*8;
  f32x4 d0 = {0.f,0.f,0.f,0.f}, d1 = d0, d2 = d0, d3 = d0;
  const int rowc = lane & 7;
  const int lg = lane >> 4;
  #pragma unroll 2
  for (int ks = 0; ks < KSW; ks++){
    const int ksg = wave*KSW + ks;
    uint4 braw = x4[(ksg*4 + lg)*8 + rowc];
    f16x8 bf = asf8(braw);
    uint4 a0 = wct[(0*KST + ksg)*64 + lane];
    uint4 a1 = wct[(1*KST + ksg)*64 + lane];
    uint4 a2 = wct[(2*KST + ksg)*64 + lane];
    uint4 a3 = wct[(3*KST + ksg)*64 + lane];
    d0 = __builtin_amdgcn_mfma_f32_16x16x32_f16(asf8(a0), bf, d0, 0, 0, 0);
    d1 = __builtin_amdgcn_mfma_f32_16x16x32_f16(asf8(a1), bf, d1, 0, 0, 0);
    d2 = __builtin_amdgcn_mfma_f32_16x16x32_f16(asf8(a2), bf, d2, 0, 0, 0);
    d3 = __builtin_amdgcn_mfma_f32_16x16x32_f16(asf8(a3), bf, d3, 0, 0, 0);
  }
  const int j = lane & 15;         // batch col (C/D: col=lane&15, row=(l>>4)*4+r)
  if (j < 8){
    const int ib = (lane >> 4) * 4;
    #pragma unroll
    for (int r = 0; r < 4; r++){
      redW[wave*512 + (( 0 + ib + r)*8) + j] = d0[r];
      redW[wave*512 + ((16 + ib + r)*8) + j] = d1[r];
      redW[wave*512 + ((32 + ib + r)*8) + j] = d2[r];
      redW[wave*512 + ((48 + ib + r)*8) + j] = d3[r];
    }
  }
}

// LDS map (147.6 KB):
//   [0,      50176) att1L  bf16[49][512]  resident (P2 identity: b=blk>>2,q=blk&3)
//   [50176, 105472) encT2  h2[512][27]    resident
//   [105472,107520) fwL    f32[512]       resident
//   [107520,108032) cL     f32[16][8]     persistent LSTM cell slice
//   [108032,108096) sbL    int[16]        octet sort_ind[0..8) + dec_len[8..16)
//   [108096,   ...) SCRATCH (phase-local, aliased):
//     GEMM: xH8 f16 chunk-major [K/8][8] (P1: 8KB, P3: 24KB) at +0
//           redW f32[8][512] (16KB) at +24576; gLs f32[512] at +40960 (P3)
//     P2: a2L[512] gateL[512] eL[256] alphaL[256] alpha2L[32] at +0
__global__ __launch_bounds__(NTHR, 2) void dec_kernel(KP p){
  __shared__ __align__(16) char smem_raw[151104];
  unsigned short* att1L = (unsigned short*)smem_raw;
  unsigned* encT2  = (unsigned*)(smem_raw + 50176);
  float* fwL       = (float*)(smem_raw + 105472);
  float* cL        = (float*)(smem_raw + 107520);
  int*   sbL       = (int*)(smem_raw + 108032);
  char* SCR        = smem_raw + 108096;
  uint4* xH8_4     = (uint4*)SCR;
  float* redW      = (float*)(SCR + 24576);
  float* gLs       = (float*)(SCR + 40960);
  float* a2L       = (float*)SCR;                    // P2
  float* gateL     = (float*)(SCR + 2048);
  float* eL        = (float*)(SCR + 4096);
  float* alphaL    = (float*)(SCR + 5120);
  unsigned* alpha2L= (unsigned*)(SCR + 6144);

  const int blk  = blockIdx.x;
  const int tid  = threadIdx.x;
  const int lane = tid & 63;
  const int wave = tid >> 6;
  // P2 identity
  const int b    = blk >> 2;
  const int q    = blk & 3;
  // P1/P3 identity: column-tile x batch-octet
  const int ct   = blk & 31;          // 0..31  (also octet rank)
  const int bt   = blk >> 5;          // 0..7   (also octet id)

  // ---------------- Pre0: stable descending argsort + caps gather ----------------
  if (blk == 0){
    if (tid < B_){
      int lb = p.clen[tid];
      int rank = 0;
      for (int j = 0; j < B_; j++){
        int lj = p.clen[j];
        rank += (lj > lb) || (lj == lb && j < tid);
      }
      p.sort_ind[rank] = tid;
      p.dec_len[rank]  = lb - 1;
      p.out[OUT_SORT + rank] = (float)tid;
    }
    __syncthreads();
    for (int idx = tid; idx < B_*L_; idx += NTHR){
      int bb = idx / L_;
      int l = idx - bb*L_;
      int sbv = p.sort_ind[bb];
      p.out[OUT_CAPS + idx] = (float)p.caps[sbv*L_ + l];
    }
  }
  gridbar(p.bar, blk);

  const int sb  = p.sort_ind[b];
  const int dlb = p.dec_len[b];

  // ---------------- Pre1: att1 = enc_s @ enc_att_w^T + b (196 tiles) + mean (64) ----------------
  for (int task = blk; task < 260; task += NBLK){
    if (task < 196){
      const int r0 = task*64;
      float* wL = (float*)smem_raw;             // [512][33]
      float* eLt = (float*)smem_raw + 512*33;   // [64][33]
      const int tx = tid & 31, ty = tid >> 5;   // ty<16
      float acc[4][16];
      #pragma unroll
      for (int i=0;i<4;i++)
        #pragma unroll
        for (int j=0;j<16;j++) acc[i][j] = 0.f;
      for (int k0 = 0; k0 < 512; k0 += 32){
        __syncthreads();
        for (int i = tid; i < 512*32; i += NTHR){
          int a = i >> 5, kk = i & 31;
          wL[a*33 + kk] = p.eaw[a*512 + k0 + kk];
        }
        for (int i = tid; i < 64*32; i += NTHR){
          int rl = i >> 5, kk = i & 31;
          int r = r0 + rl;
          int bb = r / 196;
          int pp = r - bb*196;
          int sbv = p.sort_ind[bb];
          eLt[rl*33 + kk] = p.enc[((size_t)sbv*196 + pp)*512 + k0 + kk];
        }
        __syncthreads();
        for (int kk = 0; kk < 32; kk++){
          float ev[4];
          #pragma unroll
          for (int ii=0;ii<4;ii++) ev[ii] = eLt[(ty*4+ii)*33 + kk];
          #pragma unroll
          for (int jj=0;jj<16;jj++){
            float wv = wL[(tx + 32*jj)*33 + kk];
            #pragma unroll
            for (int ii=0;ii<4;ii++) acc[ii][jj] = fmaf(ev[ii], wv, acc[ii][jj]);
          }
        }
      }
      #pragma unroll
      for (int jj=0;jj<16;jj++){
        int a = tx + 32*jj;
        float bbv = p.eab[a];
        #pragma unroll
        for (int ii=0;ii<4;ii++){
          int r = r0 + ty*4 + ii;
          p.att1[(size_t)r*512 + a] = acc[ii][jj] + bbv;
        }
      }
      __syncthreads();
    } else {
      int bb = task - 196;
      int sbv = p.sort_ind[bb];
      const float* eb = p.enc + (size_t)sbv*P_*E_;
      for (int e = tid; e < E_; e += NTHR){
        float s = 0.f;
        for (int pp = 0; pp < P_; pp++) s += eb[pp*E_ + e];
        p.mnT[bb*512 + e] = s * (1.f/196.f);
      }
    }
  }
  gridbar(p.bar, blk);

  // ---------------- Pre2: residents + MFMA weight fragments + h0/c0 ----------------
  // (a) P2 residents
  for (int idx = tid; idx < 49*512; idx += NTHR){
    int pp = idx >> 9, a = idx & 511;
    att1L[idx] = f2bf(p.att1[((size_t)(b*196 + q*49 + pp))*512 + a]);
  }
  for (int i = tid; i < 512*25; i += NTHR){
    int p2 = i >> 9, e = i & 511;
    int pr0 = q*49 + 2*p2;
    float e0 = p.enc[((size_t)sb*196 + pr0)*512 + e];
    float e1 = (2*p2+1 < 49) ? p.enc[((size_t)sb*196 + pr0 + 1)*512 + e] : 0.f;
    encT2[e*27 + p2] = packh2(e0, e1);
  }
  fwL[tid] = p.faw[tid];
  if (tid < 8)       sbL[tid]     = p.sort_ind[bt*8 + tid];
  else if (tid < 16) sbL[tid]     = p.dec_len[bt*8 + (tid-8)];
  // (b) wA3 fragments (2 MB in wA2 buffer): cols 0-511 daw, 512-1023 fbw,
  //     1024-2023 fcw, rest zero.  One uint4 per thread.
  {
    int gidx = blk*512 + tid;                 // 0..131071
    int l = gidx & 63, ks = (gidx >> 6) & 15, ctmt = gidx >> 10;
    int cg = (ctmt >> 2)*64 + (ctmt & 3)*16 + (l & 15);
    int k  = ks*32 + ((l >> 4) << 3);
    uint4 o = {0u,0u,0u,0u};
    const float* src = nullptr;
    if (cg < 512)        src = p.daw + (size_t)cg*512 + k;
    else if (cg < 1024)  src = p.fbw + (size_t)(cg-512)*512 + k;
    else if (cg < 2024)  src = p.fcw + (size_t)(cg-1024)*512 + k;
    if (src){
      const float4* s4 = (const float4*)src;
      float4 f0 = s4[0], f1 = s4[1];
      o.x = packh2(f0.x,f0.y); o.y = packh2(f0.z,f0.w);
      o.z = packh2(f1.x,f1.y); o.w = packh2(f1.z,f1.w);
    }
    ((uint4*)p.wA2)[gidx] = o;
  }
  // (c) wG3 fragments (6 MB in wG2 buffer): col cg = j*4+g -> row g*512+j.
  for (int s = 0; s < 3; s++){
    int gidx = blk*1536 + s*512 + tid;        // 0..393215
    int l = gidx & 63, ks = (gidx >> 6) % 48, ctmt = gidx / 3072;
    int cg = (ctmt >> 2)*64 + (ctmt & 3)*16 + (l & 15);
    int jj = cg >> 2, g = cg & 3;
    int k  = ks*32 + ((l >> 4) << 3);
    const float* src = (k < 1024) ? p.wih + (size_t)(g*512+jj)*1024 + k
                                  : p.whh + (size_t)(g*512+jj)*512 + (k-1024);
    const float4* s4 = (const float4*)src;
    float4 f0 = s4[0], f1 = s4[1];
    uint4 o;
    o.x = packh2(f0.x,f0.y); o.y = packh2(f0.z,f0.w);
    o.z = packh2(f1.x,f1.y); o.w = packh2(f1.z,f1.w);
    ((uint4*)p.wG2)[gidx] = o;
  }
  // (d) h0/c0 for P3 slice (ct: 16 j's, bt: 8 b's)
  if (tid < 128){
    int jj = tid >> 3, bb2 = tid & 7;
    int b8 = bt*8 + bb2, jg = ct*16 + jj;
    const float* mrow = p.mnT + b8*512;
    const float* hw = p.ihw + (size_t)jg*512;
    const float* cw = p.icw + (size_t)jg*512;
    float ah = 0.f, ac = 0.f;
    for (int k = 0; k < 512; k++){ ah = fmaf(hw[k], mrow[k], ah); ac = fmaf(cw[k], mrow[k], ac); }
    stg_c(&p.hA[b8*512 + jg], ah + p.ihb[jg]);
    cL[jj*8 + bb2] = ac + p.icb[jg];
  }
  gridbar(p.bar, blk);

  const float fab0 = p.fab[0];
  int ep = 0;

  // ---------------- time loop ----------------
  for (int t = 0; t < T_; t++){
    const float* hR = (t & 1) ? p.hB : p.hA;   // h(t)
    float*       hW = (t & 1) ? p.hA : p.hB;   // h(t+1)

    // ======== P1: a2+gate (ct<16) | preds(t-1) (ct>=16) -- MFMA GEMV ========
    if (ct < 16 || t > 0){
      {
        const float* xsrc = (ct < 16) ? hR : p.hnG;
        int cc = tid >> 3, r = tid & 7;
        const float* src = xsrc + (size_t)(bt*8 + r)*512 + cc*8;
        float2 v0 = ldg2_c(src), v1 = ldg2_c(src+2), v2 = ldg2_c(src+4), v3 = ldg2_c(src+6);
        uint4 o;
        o.x = packh2(v0.x,v0.y); o.y = packh2(v1.x,v1.y);
        o.z = packh2(v2.x,v2.y); o.w = packh2(v3.x,v3.y);
        xH8_4[tid] = o;
      }
      __syncthreads();
      gemv_mfma<2>((const uint4*)p.wA2 + (size_t)ct*4096, xH8_4, redW, lane, wave);
      __syncthreads();
      {
        float s = 0.f;
        #pragma unroll
        for (int w8 = 0; w8 < 8; w8++) s += redW[w8*512 + tid];
        int c_local = tid >> 3, j = tid & 7, b8 = bt*8 + j;
        if (ct < 16){
          int vcl = ct*64 + c_local;
          if (vcl < 512) stg_c(&p.a2G[b8*512 + vcl], s + p.dab[vcl]);
          else           stg_c(&p.gateG[b8*512 + (vcl-512)], sigf(s + p.fbb[vcl-512]));
        } else {
          int v2i = (ct-16)*64 + c_local;
          if (v2i < 1000){
            bool mm = (t-1) < sbL[8 + j];
            p.out[OUT_PRED + ((size_t)b8*T_ + (t-1))*V_ + v2i] = mm ? (s + p.fcb[v2i]) : 0.f;
          }
        }
      }
    }
    octbar(p.flb, bt, ct, ++ep);   // B1

    // ======== P2: attention (group of 4 blocks per b) ========
    {
      a2L[tid]   = ldg_c(&p.a2G[b*512 + tid]);
      gateL[tid] = ldg_c(&p.gateG[b*512 + tid]);
      __syncthreads();
      // e for own 49 rows from bf16 att1L
      {
        float4 aA = ((float4*)a2L)[lane*2], aB = ((float4*)a2L)[lane*2+1];
        float4 fA = ((float4*)fwL)[lane*2], fB = ((float4*)fwL)[lane*2+1];
        for (int pp = wave; pp < 49; pp += 8){
          uint4 raw = ((const uint4*)att1L)[pp*64 + lane];
          float s =
            fmaxf(__uint_as_float(raw.x << 16)        + aA.x, 0.f)*fA.x +
            fmaxf(__uint_as_float(raw.x & 0xffff0000u)+ aA.y, 0.f)*fA.y +
            fmaxf(__uint_as_float(raw.y << 16)        + aA.z, 0.f)*fA.z +
            fmaxf(__uint_as_float(raw.y & 0xffff0000u)+ aA.w, 0.f)*fA.w +
            fmaxf(__uint_as_float(raw.z << 16)        + aB.x, 0.f)*fB.x +
            fmaxf(__uint_as_float(raw.z & 0xffff0000u)+ aB.y, 0.f)*fB.y +
            fmaxf(__uint_as_float(raw.w << 16)        + aB.z, 0.f)*fB.z +
            fmaxf(__uint_as_float(raw.w & 0xffff0000u)+ aB.w, 0.f)*fB.w;
          #pragma unroll
          for (int o = 32; o > 0; o >>= 1) s += __shfl_down(s, o);
          if (lane == 0) stg_c(&p.eG[b*256 + q*49 + pp], s + fab0);
        }
      }
      // group sync: e complete (flag protocol; 4 lanes poll)
      __syncthreads();
      if (tid == 0) ST_A(&p.gf[b*16 + q], t+1);
      if (tid < 4){
        while (LD_A(&p.gf[b*16 + tid]) < t+1) __builtin_amdgcn_s_sleep(1);
      }
      asm volatile("" ::: "memory");
      __syncthreads();
      if (tid < 196) eL[tid] = ldg_c(&p.eG[b*256 + tid]);
      __syncthreads();
      if (wave == 0){
        float mx = -1e30f;
        for (int i = lane; i < P_; i += 64) mx = fmaxf(mx, eL[i]);
        #pragma unroll
        for (int o = 32; o > 0; o >>= 1) mx = fmaxf(mx, __shfl_xor(mx, o));
        float sum = 0.f;
        for (int i = lane; i < P_; i += 64){
          float ex = __expf(eL[i] - mx);
          alphaL[i] = ex;
          sum += ex;
        }
        #pragma unroll
        for (int o = 32; o > 0; o >>= 1) sum += __shfl_xor(sum, o);
        float inv = 1.f / sum;
        for (int i = lane; i < P_; i += 64) alphaL[i] *= inv;
      }
      __syncthreads();
      {
        bool mb = t < dlb;
        if (tid < 49)
          p.out[OUT_ALPHA + ((size_t)b*T_ + t)*P_ + q*49 + tid] = mb ? alphaL[q*49 + tid] : 0.f;
        if (tid < 25){
          float a0 = alphaL[q*49 + 2*tid];
          float a1 = (2*tid+1 < 49) ? alphaL[q*49 + 2*tid + 1] : 0.f;
          alpha2L[tid] = packh2(a0, a1);
        }
      }
      __syncthreads();
      {
        const unsigned* ec = encT2 + tid*27;
        float s = 0.f;
        #pragma unroll 5
        for (int p2 = 0; p2 < 25; p2++)
          s = fdot2f(ash2(ec[p2]), ash2(alpha2L[p2]), s);
        // deterministic per-q partial (summed in P3 staging) -- no atomics
        stg_c(&p.aweQ[((size_t)b*4 + q)*512 + tid], gateL[tid]*s);
      }
    }
    octbar(p.flb, bt, ct, ++ep);   // B2

    // ======== P3: gates GEMM (MFMA, K=1536) + LSTM ========
    {
      {
        int cc = tid >> 3, r = tid & 7;
        int b8 = bt*8 + r;
        // iter1: emb[cap][cc*8..+8)  (const input, plain loads)
        {
          int cap = p.caps[sbL[r]*L_ + t];
          const float4* er = (const float4*)(p.emb + (size_t)cap*M_ + cc*8);
          float4 f0 = er[0], f1 = er[1];
          uint4 o;
          o.x = packh2(f0.x,f0.y); o.y = packh2(f0.z,f0.w);
          o.z = packh2(f1.x,f1.y); o.w = packh2(f1.z,f1.w);
          xH8_4[tid] = o;
        }
        // iter2: gated awe = sum of 4 q-partials (coherent loads)
        {
          const float* aw = p.aweQ + (size_t)b8*4*512 + cc*8;
          float a8[8];
          #pragma unroll
          for (int e = 0; e < 8; e += 2){
            float2 q0 = ldg2_c(aw + 0*512 + e);
            float2 q1 = ldg2_c(aw + 1*512 + e);
            float2 q2 = ldg2_c(aw + 2*512 + e);
            float2 q3 = ldg2_c(aw + 3*512 + e);
            a8[e]   = (q0.x + q1.x) + (q2.x + q3.x);
            a8[e+1] = (q0.y + q1.y) + (q2.y + q3.y);
          }
          uint4 o;
          o.x = packh2(a8[0],a8[1]); o.y = packh2(a8[2],a8[3]);
          o.z = packh2(a8[4],a8[5]); o.w = packh2(a8[6],a8[7]);
          xH8_4[512 + tid] = o;
        }
        // iter3: h(t)
        {
          const float* hs = hR + (size_t)b8*512 + cc*8;
          float2 v0 = ldg2_c(hs), v1 = ldg2_c(hs+2), v2 = ldg2_c(hs+4), v3 = ldg2_c(hs+6);
          uint4 o;
          o.x = packh2(v0.x,v0.y); o.y = packh2(v1.x,v1.y);
          o.z = packh2(v2.x,v2.y); o.w = packh2(v3.x,v3.y);
          xH8_4[1024 + tid] = o;
        }
      }
      __syncthreads();
      gemv_mfma<6>((const uint4*)p.wG2 + (size_t)ct*12288, xH8_4, redW, lane, wave);
      __syncthreads();
      {
        float s = 0.f;
        #pragma unroll
        for (int w8 = 0; w8 < 8; w8++) s += redW[w8*512 + tid];
        gLs[(tid & 7)*64 + (tid >> 3)] = s;
      }
      __syncthreads();
      if (tid < 128){
        int jj = tid >> 3, bb2 = tid & 7;
        int b8 = bt*8 + bb2, jg = ct*16 + jj;
        float g0 = gLs[bb2*64 + jj*4+0] + p.bih[jg]        + p.bhh[jg];
        float g1 = gLs[bb2*64 + jj*4+1] + p.bih[512 + jg]  + p.bhh[512 + jg];
        float g2 = gLs[bb2*64 + jj*4+2] + p.bih[1024 + jg] + p.bhh[1024 + jg];
        float g3 = gLs[bb2*64 + jj*4+3] + p.bih[1536 + jg] + p.bhh[1536 + jg];
        float i_s = sigf(g0), f_s = sigf(g1), g_t = tanhf_(g2), o_s = sigf(g3);
        float c_old = cL[jj*8 + bb2];
        float c_new = f_s*c_old + i_s*g_t;
        float h_new = o_s*tanhf_(c_new);
        bool m = t < sbL[8 + bb2];
        float h_old = ldg_c(&hR[b8*512 + jg]);
        cL[jj*8 + bb2] = m ? c_new : c_old;
        stg_c(&p.hnG[b8*512 + jg], h_new);
        stg_c(&hW[b8*512 + jg], m ? h_new : h_old);
      }
    }
    octbar(p.flb, bt, ct, ++ep);   // B0 (h(t+1), hn(t) published)
  }

  // ---- final preds for t = T-1 ----
  if (ct >= 16){
    {
      int cc = tid >> 3, r = tid & 7;
      const float* src = p.hnG + (size_t)(bt*8 + r)*512 + cc*8;
      float2 v0 = ldg2_c(src), v1 = ldg2_c(src+2), v2 = ldg2_c(src+4), v3 = ldg2_c(src+6);
      uint4 o;
      o.x = packh2(v0.x,v0.y); o.y = packh2(v1.x,v1.y);
      o.z = packh2(v2.x,v2.y); o.w = packh2(v3.x,v3.y);
      xH8_4[tid] = o;
    }
    __syncthreads();
    gemv_mfma<2>((const uint4*)p.wA2 + (size_t)ct*4096, xH8_4, redW, lane, wave);
    __syncthreads();
    {
      float s = 0.f;
      #pragma unroll
      for (int w8 = 0; w8 < 8; w8++) s += redW[w8*512 + tid];
      int c_local = tid >> 3, j = tid & 7, b8 = bt*8 + j;
      int v2i = (ct-16)*64 + c_local;
      if (v2i < 1000){
        bool mm = (T_-1) < sbL[8 + j];
        p.out[OUT_PRED + ((size_t)b8*T_ + (T_-1))*V_ + v2i] = mm ? (s + p.fcb[v2i]) : 0.f;
      }
    }
  }
}

extern "C" void kernel_launch(void* const* d_in, const int* in_sizes, int n_in,
                              void* d_out, int out_size, void* d_ws, size_t ws_size,
                              hipStream_t stream){
  (void)in_sizes; (void)n_in; (void)out_size; (void)ws_size;
  KP p;
  p.enc  = (const float*)d_in[0];
  p.caps = (const int*)  d_in[1];
  p.clen = (const int*)  d_in[2];
  p.emb  = (const float*)d_in[3];
  p.eaw  = (const float*)d_in[4];  p.eab = (const float*)d_in[5];
  p.daw  = (const float*)d_in[6];  p.dab = (const float*)d_in[7];
  p.faw  = (const float*)d_in[8];  p.fab = (const float*)d_in[9];
  p.wih  = (const float*)d_in[10]; p.bih = (const float*)d_in[11];
  p.whh  = (const float*)d_in[12]; p.bhh = (const float*)d_in[13];
  p.ihw  = (const float*)d_in[14]; p.ihb = (const float*)d_in[15];
  p.icw  = (const float*)d_in[16]; p.icb = (const float*)d_in[17];
  p.fbw  = (const float*)d_in[18]; p.fbb = (const float*)d_in[19];
  p.fcw  = (const float*)d_in[20]; p.fcb = (const float*)d_in[21];
  p.out  = (float*)d_out;

  char* ws = (char*)d_ws;
  size_t off = 0;
  p.bar = (int*)(ws + off); off += 1024;     // fenced pre-barrier (global)
  p.flb = (int*)(ws + off); off += 8*64*4;   // octet flag barrier
  p.gf  = (int*)(ws + off); off += 64*16*4;  // per-b group flags
  size_t zero_bytes = off;
  p.sort_ind = (int*)(ws + off); off += 64*4;
  p.dec_len  = (int*)(ws + off); off += 64*4;
  off = (off + 255) & ~(size_t)255;
  p.mnT   = (float*)(ws + off); off += (size_t)B_*512*4;
  p.hA    = (float*)(ws + off); off += (size_t)B_*512*4;
  p.hB    = (float*)(ws + off); off += (size_t)B_*512*4;
  p.hnG   = (float*)(ws + off); off += (size_t)B_*512*4;
  p.a2G   = (float*)(ws + off); off += (size_t)B_*512*4;
  p.gateG = (float*)(ws + off); off += (size_t)B_*512*4;
  p.aweQ  = (float*)(ws + off); off += (size_t)B_*4*512*4;
  p.eG    = (float*)(ws + off); off += (size_t)B_*256*4;
  p.att1  = (float*)(ws + off); off += (size_t)B_*P_*A_*4;
  p.wA2   = (unsigned*)(ws + off); off += (size_t)256*2048*4;   // wA3 frags (2 MB)
  p.wG2   = (unsigned*)(ws + off); off += (size_t)768*2048*4;   // wG3 frags (6 MB)

  hipMemsetAsync(ws, 0, zero_bytes, stream);

  void* args[] = { (void*)&p };
  hipLaunchCooperativeKernel((const void*)dec_kernel,
                             dim3(NBLK), dim3(NTHR), args, 0, stream);
}

// Round 4
// 5616.978 us; speedup vs baseline: 2.2610x; 1.0031x over previous
//
#include <hip/hip_runtime.h>
#include <cstdint>
#include <cstddef>

#define NBLK 256
#define NTHR 512
#define B_ 64
#define P_ 196
#define E_ 512
#define A_ 512
#define D_ 512
#define M_ 512
#define V_ 1000
#define L_ 257
#define T_ 256

#define OUT_PRED  0
#define OUT_CAPS  (B_*T_*V_)                 /* 16,384,000 */
#define OUT_ALPHA (OUT_CAPS + B_*L_)         /* 16,400,448 */
#define OUT_SORT  (OUT_ALPHA + B_*T_*P_)     /* 19,611,712 */

typedef _Float16 h2 __attribute__((ext_vector_type(2)));
typedef _Float16 f16x8 __attribute__((ext_vector_type(8)));
typedef float f32x4 __attribute__((ext_vector_type(4)));

struct KP {
  const float* enc; const int* caps; const int* clen;
  const float* emb;
  const float* eaw; const float* eab;
  const float* daw; const float* dab;
  const float* faw; const float* fab;
  const float* wih; const float* bih;
  const float* whh; const float* bhh;
  const float* ihw; const float* ihb;
  const float* icw; const float* icb;
  const float* fbw; const float* fbb;
  const float* fcw; const float* fcb;
  float* out;
  int* bar; int* flb; int* gf;
  int* sort_ind; int* dec_len;
  float* mnT; float* hA; float* hB; float* hnG;
  float* a2G; float* gateG; float* aweQ; float* eG; float* att1;
};

__device__ __forceinline__ float sigf(float x){ return 1.f/(1.f+__expf(-x)); }
__device__ __forceinline__ float tanhf_(float x){
  float ax = fabsf(x);
  float e = __expf(-2.f*ax);
  float r = (1.f-e)/(1.f+e);
  return x < 0.f ? -r : r;
}
__device__ __forceinline__ unsigned short f2bf(float x){
  unsigned u = __float_as_uint(x);
  unsigned r = (u + 0x7fffu + ((u >> 16) & 1u)) >> 16;   // RNE
  return (unsigned short)r;
}
__device__ __forceinline__ float fdot2f(h2 a, h2 b, float c){
#if __has_builtin(__builtin_amdgcn_fdot2)
  return __builtin_amdgcn_fdot2(a, b, c, false);
#else
  return c + (float)a.x*(float)b.x + (float)a.y*(float)b.y;
#endif
}
__device__ __forceinline__ unsigned packh2(float a, float b){
  h2 v; v.x = (_Float16)a; v.y = (_Float16)b;
  return __builtin_bit_cast(unsigned, v);
}
__device__ __forceinline__ h2 ash2(unsigned u){ return __builtin_bit_cast(h2, u); }
__device__ __forceinline__ f16x8 asf8(uint4 u){ return __builtin_bit_cast(f16x8, u); }

#define LD_A(p)     __hip_atomic_load((p), __ATOMIC_RELAXED, __HIP_MEMORY_SCOPE_AGENT)
#define ST_A(p,v)   __hip_atomic_store((p),(v), __ATOMIC_RELAXED, __HIP_MEMORY_SCOPE_AGENT)
#define ST_REL(p,v) __hip_atomic_store((p),(v), __ATOMIC_RELEASE, __HIP_MEMORY_SCOPE_AGENT)
#define FAA(p)      __hip_atomic_fetch_add((p),1, __ATOMIC_RELAXED, __HIP_MEMORY_SCOPE_AGENT)
__device__ __forceinline__ float ldg_c(const float* p){
  return __hip_atomic_load(p, __ATOMIC_RELAXED, __HIP_MEMORY_SCOPE_AGENT);
}
__device__ __forceinline__ float2 ldg2_c(const float* p){
  unsigned long long u = __hip_atomic_load((const unsigned long long*)p,
                       __ATOMIC_RELAXED, __HIP_MEMORY_SCOPE_AGENT);
  return __builtin_bit_cast(float2, u);
}
__device__ __forceinline__ void stg_c(float* p, float v){
  __hip_atomic_store(p, v, __ATOMIC_RELAXED, __HIP_MEMORY_SCOPE_AGENT);
}

// Fenced grid barrier -- pre-phase only (global, 3 uses).
__device__ __forceinline__ void gridbar(int* bar, int blk){
  __syncthreads();
  if (threadIdx.x == 0){
    __builtin_amdgcn_fence(__ATOMIC_RELEASE, "agent");
    int s = LD_A(&bar[144]);
    int* leaf = &bar[(blk & 7)*16];
    if (FAA(leaf) == 31){
      ST_A(leaf, 0);
      if (FAA(&bar[128]) == 7){
        ST_A(&bar[128], 0);
        ST_REL(&bar[144], s+1);
      }
    }
    while (LD_A(&bar[144]) == s) __builtin_amdgcn_s_sleep(2);
    __builtin_amdgcn_fence(__ATOMIC_ACQUIRE, "agent");
  }
  __syncthreads();
}

// Octet-scoped flat flag barrier for the time loop: each block
// release-stores its monotonic epoch to its own flag; 32 lanes poll.
__device__ __forceinline__ void octbar(int* fl, int O, int r, int ep){
  __syncthreads();
  if (threadIdx.x == 0) ST_A(&fl[O*64 + r], ep);
  if (threadIdx.x < 32){
    while (LD_A(&fl[O*64 + (int)threadIdx.x]) < ep) __builtin_amdgcn_s_sleep(2);
  }
  asm volatile("" ::: "memory");
  __syncthreads();
}

// ---------------- MFMA K-split GEMV, register-resident weights ----------------
// Per block: D[64 cols][8 batches] via 4 M-tiles of mfma_f32_16x16x32_f16.
// A frags live in VGPRs (wfr[mt][ks], static-indexed); B (K=32 x 16 batches)
// from LDS chunk-major f16 [K/8][8]: one ds_read_b128 per K-step per lane.
// K split 8 ways across waves; partials reduced through redW f32[8][512];
// slot = c_local*8 + j == reduce tid.
template<int KSW>
__device__ __forceinline__ void gemv_regs(const uint4 (&wfr)[4][KSW],
                                          const uint4* __restrict__ x4,
                                          float* redW, int lane, int wave){
  f32x4 d0 = {0.f,0.f,0.f,0.f}, d1 = d0, d2 = d0, d3 = d0;
  const int rowc = lane & 7;
  const int lg = lane >> 4;
  #pragma unroll
  for (int ks = 0; ks < KSW; ks++){
    const int ksg = wave*KSW + ks;
    f16x8 bf = asf8(x4[(ksg*4 + lg)*8 + rowc]);
    d0 = __builtin_amdgcn_mfma_f32_16x16x32_f16(asf8(wfr[0][ks]), bf, d0, 0, 0, 0);
    d1 = __builtin_amdgcn_mfma_f32_16x16x32_f16(asf8(wfr[1][ks]), bf, d1, 0, 0, 0);
    d2 = __builtin_amdgcn_mfma_f32_16x16x32_f16(asf8(wfr[2][ks]), bf, d2, 0, 0, 0);
    d3 = __builtin_amdgcn_mfma_f32_16x16x32_f16(asf8(wfr[3][ks]), bf, d3, 0, 0, 0);
  }
  const int j = lane & 15;         // batch col (C/D: col=lane&15, row=(l>>4)*4+r)
  if (j < 8){
    const int ib = (lane >> 4) * 4;
    #pragma unroll
    for (int r = 0; r < 4; r++){
      redW[wave*512 + (( 0 + ib + r)*8) + j] = d0[r];
      redW[wave*512 + ((16 + ib + r)*8) + j] = d1[r];
      redW[wave*512 + ((32 + ib + r)*8) + j] = d2[r];
      redW[wave*512 + ((48 + ib + r)*8) + j] = d3[r];
    }
  }
}

// LDS map (147.6 KB):
//   [0,      50176) att1L  bf16[49][512]  resident (P2 identity: b=blk>>2,q=blk&3)
//   [50176, 105472) encT2  h2[512][27]    resident
//   [105472,107520) fwL    f32[512]       resident
//   [107520,108032) cL     f32[16][8]     persistent LSTM cell slice
//   [108032,108096) sbL    int[16]        octet sort_ind[0..8) + dec_len[8..16)
//   [108096,   ...) SCRATCH (phase-local, aliased):
//     GEMM: xH8 f16 chunk-major [K/8][8] (P1: 8KB, P3: 24KB) at +0
//           redW f32[8][512] (16KB) at +24576; gLs f32[512] at +40960 (P3)
//     P2: a2L[512] gateL[512] eL[256] alphaL[256] alpha2L[32] at +0
__global__ __launch_bounds__(NTHR, 2) void dec_kernel(KP p){
  __shared__ __align__(16) char smem_raw[151104];
  unsigned short* att1L = (unsigned short*)smem_raw;
  unsigned* encT2  = (unsigned*)(smem_raw + 50176);
  float* fwL       = (float*)(smem_raw + 105472);
  float* cL        = (float*)(smem_raw + 107520);
  int*   sbL       = (int*)(smem_raw + 108032);
  char* SCR        = smem_raw + 108096;
  uint4* xH8_4     = (uint4*)SCR;
  float* redW      = (float*)(SCR + 24576);
  float* gLs       = (float*)(SCR + 40960);
  float* a2L       = (float*)SCR;                    // P2
  float* gateL     = (float*)(SCR + 2048);
  float* eL        = (float*)(SCR + 4096);
  float* alphaL    = (float*)(SCR + 5120);
  unsigned* alpha2L= (unsigned*)(SCR + 6144);

  const int blk  = blockIdx.x;
  const int tid  = threadIdx.x;
  const int lane = tid & 63;
  const int wave = tid >> 6;
  // P2 identity
  const int b    = blk >> 2;
  const int q    = blk & 3;
  // P1/P3 identity: column-tile x batch-octet
  const int ct   = blk & 31;          // 0..31  (also octet rank)
  const int bt   = blk >> 5;          // 0..7   (also octet id)

  // ---------------- Pre0: stable descending argsort + caps gather ----------------
  if (blk == 0){
    if (tid < B_){
      int lb = p.clen[tid];
      int rank = 0;
      for (int j = 0; j < B_; j++){
        int lj = p.clen[j];
        rank += (lj > lb) || (lj == lb && j < tid);
      }
      p.sort_ind[rank] = tid;
      p.dec_len[rank]  = lb - 1;
      p.out[OUT_SORT + rank] = (float)tid;
    }
    __syncthreads();
    for (int idx = tid; idx < B_*L_; idx += NTHR){
      int bb = idx / L_;
      int l = idx - bb*L_;
      int sbv = p.sort_ind[bb];
      p.out[OUT_CAPS + idx] = (float)p.caps[sbv*L_ + l];
    }
  }
  gridbar(p.bar, blk);

  const int sb  = p.sort_ind[b];
  const int dlb = p.dec_len[b];

  // ---------------- Pre1: att1 = enc_s @ enc_att_w^T + b (196 tiles) + mean (64) ----------------
  for (int task = blk; task < 260; task += NBLK){
    if (task < 196){
      const int r0 = task*64;
      float* wL = (float*)smem_raw;             // [512][33]
      float* eLt = (float*)smem_raw + 512*33;   // [64][33]
      const int tx = tid & 31, ty = tid >> 5;   // ty<16
      float acc[4][16];
      #pragma unroll
      for (int i=0;i<4;i++)
        #pragma unroll
        for (int j=0;j<16;j++) acc[i][j] = 0.f;
      for (int k0 = 0; k0 < 512; k0 += 32){
        __syncthreads();
        for (int i = tid; i < 512*32; i += NTHR){
          int a = i >> 5, kk = i & 31;
          wL[a*33 + kk] = p.eaw[a*512 + k0 + kk];
        }
        for (int i = tid; i < 64*32; i += NTHR){
          int rl = i >> 5, kk = i & 31;
          int r = r0 + rl;
          int bb = r / 196;
          int pp = r - bb*196;
          int sbv = p.sort_ind[bb];
          eLt[rl*33 + kk] = p.enc[((size_t)sbv*196 + pp)*512 + k0 + kk];
        }
        __syncthreads();
        for (int kk = 0; kk < 32; kk++){
          float ev[4];
          #pragma unroll
          for (int ii=0;ii<4;ii++) ev[ii] = eLt[(ty*4+ii)*33 + kk];
          #pragma unroll
          for (int jj=0;jj<16;jj++){
            float wv = wL[(tx + 32*jj)*33 + kk];
            #pragma unroll
            for (int ii=0;ii<4;ii++) acc[ii][jj] = fmaf(ev[ii], wv, acc[ii][jj]);
          }
        }
      }
      #pragma unroll
      for (int jj=0;jj<16;jj++){
        int a = tx + 32*jj;
        float bbv = p.eab[a];
        #pragma unroll
        for (int ii=0;ii<4;ii++){
          int r = r0 + ty*4 + ii;
          p.att1[(size_t)r*512 + a] = acc[ii][jj] + bbv;
        }
      }
      __syncthreads();
    } else {
      int bb = task - 196;
      int sbv = p.sort_ind[bb];
      const float* eb = p.enc + (size_t)sbv*P_*E_;
      for (int e = tid; e < E_; e += NTHR){
        float s = 0.f;
        for (int pp = 0; pp < P_; pp++) s += eb[pp*E_ + e];
        p.mnT[bb*512 + e] = s * (1.f/196.f);
      }
    }
  }
  gridbar(p.bar, blk);

  // ---------------- Pre2: residents + persistent weight frags + h0/c0 ----------------
  // (a) P2 residents
  for (int idx = tid; idx < 49*512; idx += NTHR){
    int pp = idx >> 9, a = idx & 511;
    att1L[idx] = f2bf(p.att1[((size_t)(b*196 + q*49 + pp))*512 + a]);
  }
  for (int i = tid; i < 512*25; i += NTHR){
    int p2 = i >> 9, e = i & 511;
    int pr0 = q*49 + 2*p2;
    float e0 = p.enc[((size_t)sb*196 + pr0)*512 + e];
    float e1 = (2*p2+1 < 49) ? p.enc[((size_t)sb*196 + pr0 + 1)*512 + e] : 0.f;
    encT2[e*27 + p2] = packh2(e0, e1);
  }
  fwL[tid] = p.faw[tid];
  if (tid < 8)       sbL[tid]     = p.sort_ind[bt*8 + tid];
  else if (tid < 16) sbL[tid]     = p.dec_len[bt*8 + (tid-8)];
  // (b) persistent register fragments (loaded ONCE, live across the loop).
  //   wa[mt][ks]: cols ct*64+mt*16+(lane&15); cg<512 daw, <1024 fbw, <2024 fcw.
  //   wg[mt][ks]: col cg -> (j=cg>>2, g=cg&3) -> weight row g*512+j; K=1536.
  uint4 wa[4][2];
  uint4 wg[4][6];
  {
    const int cgb = ct*64 + (lane & 15);
    const int kof = (lane >> 4) << 3;
    #pragma unroll
    for (int mt = 0; mt < 4; mt++){
      int cg = cgb + mt*16;
      #pragma unroll
      for (int ks = 0; ks < 2; ks++){
        int k = (wave*2 + ks)*32 + kof;
        uint4 o = {0u,0u,0u,0u};
        const float* src = nullptr;
        if (cg < 512)        src = p.daw + (size_t)cg*512 + k;
        else if (cg < 1024)  src = p.fbw + (size_t)(cg-512)*512 + k;
        else if (cg < 2024)  src = p.fcw + (size_t)(cg-1024)*512 + k;
        if (src){
          const float4* s4 = (const float4*)src;
          float4 f0 = s4[0], f1 = s4[1];
          o.x = packh2(f0.x,f0.y); o.y = packh2(f0.z,f0.w);
          o.z = packh2(f1.x,f1.y); o.w = packh2(f1.z,f1.w);
        }
        wa[mt][ks] = o;
      }
      int jj = cg >> 2, g = cg & 3;
      #pragma unroll
      for (int ks = 0; ks < 6; ks++){
        int k = (wave*6 + ks)*32 + kof;
        const float* src = (k < 1024) ? p.wih + (size_t)(g*512+jj)*1024 + k
                                      : p.whh + (size_t)(g*512+jj)*512 + (k-1024);
        const float4* s4 = (const float4*)src;
        float4 f0 = s4[0], f1 = s4[1];
        uint4 o;
        o.x = packh2(f0.x,f0.y); o.y = packh2(f0.z,f0.w);
        o.z = packh2(f1.x,f1.y); o.w = packh2(f1.z,f1.w);
        wg[mt][ks] = o;
      }
    }
  }
  // (c) h0/c0 for P3 slice (ct: 16 j's, bt: 8 b's)
  if (tid < 128){
    int jj = tid >> 3, bb2 = tid & 7;
    int b8 = bt*8 + bb2, jg = ct*16 + jj;
    const float* mrow = p.mnT + b8*512;
    const float* hw = p.ihw + (size_t)jg*512;
    const float* cw = p.icw + (size_t)jg*512;
    float ah = 0.f, ac = 0.f;
    for (int k = 0; k < 512; k++){ ah = fmaf(hw[k], mrow[k], ah); ac = fmaf(cw[k], mrow[k], ac); }
    stg_c(&p.hA[b8*512 + jg], ah + p.ihb[jg]);
    cL[jj*8 + bb2] = ac + p.icb[jg];
  }
  gridbar(p.bar, blk);

  const float fab0 = p.fab[0];
  int ep = 0;

  // ---------------- time loop ----------------
  for (int t = 0; t < T_; t++){
    const float* hR = (t & 1) ? p.hB : p.hA;   // h(t)
    float*       hW = (t & 1) ? p.hA : p.hB;   // h(t+1)

    // ======== P1: a2+gate (ct<16) | preds(t-1) (ct>=16) -- MFMA GEMV ========
    if (ct < 16 || t > 0){
      {
        const float* xsrc = (ct < 16) ? hR : p.hnG;
        int cc = tid >> 3, r = tid & 7;
        const float* src = xsrc + (size_t)(bt*8 + r)*512 + cc*8;
        float2 v0 = ldg2_c(src), v1 = ldg2_c(src+2), v2 = ldg2_c(src+4), v3 = ldg2_c(src+6);
        uint4 o;
        o.x = packh2(v0.x,v0.y); o.y = packh2(v1.x,v1.y);
        o.z = packh2(v2.x,v2.y); o.w = packh2(v3.x,v3.y);
        xH8_4[tid] = o;
      }
      __syncthreads();
      gemv_regs<2>(wa, xH8_4, redW, lane, wave);
      __syncthreads();
      {
        float s = 0.f;
        #pragma unroll
        for (int w8 = 0; w8 < 8; w8++) s += redW[w8*512 + tid];
        int c_local = tid >> 3, j = tid & 7, b8 = bt*8 + j;
        if (ct < 16){
          int vcl = ct*64 + c_local;
          if (vcl < 512) stg_c(&p.a2G[b8*512 + vcl], s + p.dab[vcl]);
          else           stg_c(&p.gateG[b8*512 + (vcl-512)], sigf(s + p.fbb[vcl-512]));
        } else {
          int v2i = (ct-16)*64 + c_local;
          if (v2i < 1000){
            bool mm = (t-1) < sbL[8 + j];
            p.out[OUT_PRED + ((size_t)b8*T_ + (t-1))*V_ + v2i] = mm ? (s + p.fcb[v2i]) : 0.f;
          }
        }
      }
    }
    octbar(p.flb, bt, ct, ++ep);   // B1

    // ======== P2: attention (group of 4 blocks per b) ========
    {
      a2L[tid]   = ldg_c(&p.a2G[b*512 + tid]);
      gateL[tid] = ldg_c(&p.gateG[b*512 + tid]);
      __syncthreads();
      // e for own 49 rows from bf16 att1L
      {
        float4 aA = ((float4*)a2L)[lane*2], aB = ((float4*)a2L)[lane*2+1];
        float4 fA = ((float4*)fwL)[lane*2], fB = ((float4*)fwL)[lane*2+1];
        for (int pp = wave; pp < 49; pp += 8){
          uint4 raw = ((const uint4*)att1L)[pp*64 + lane];
          float s =
            fmaxf(__uint_as_float(raw.x << 16)        + aA.x, 0.f)*fA.x +
            fmaxf(__uint_as_float(raw.x & 0xffff0000u)+ aA.y, 0.f)*fA.y +
            fmaxf(__uint_as_float(raw.y << 16)        + aA.z, 0.f)*fA.z +
            fmaxf(__uint_as_float(raw.y & 0xffff0000u)+ aA.w, 0.f)*fA.w +
            fmaxf(__uint_as_float(raw.z << 16)        + aB.x, 0.f)*fB.x +
            fmaxf(__uint_as_float(raw.z & 0xffff0000u)+ aB.y, 0.f)*fB.y +
            fmaxf(__uint_as_float(raw.w << 16)        + aB.z, 0.f)*fB.z +
            fmaxf(__uint_as_float(raw.w & 0xffff0000u)+ aB.w, 0.f)*fB.w;
          #pragma unroll
          for (int o = 32; o > 0; o >>= 1) s += __shfl_down(s, o);
          if (lane == 0) stg_c(&p.eG[b*256 + q*49 + pp], s + fab0);
        }
      }
      // group sync: e complete (flag protocol; 4 lanes poll)
      __syncthreads();
      if (tid == 0) ST_A(&p.gf[b*16 + q], t+1);
      if (tid < 4){
        while (LD_A(&p.gf[b*16 + tid]) < t+1) __builtin_amdgcn_s_sleep(1);
      }
      asm volatile("" ::: "memory");
      __syncthreads();
      if (tid < 196) eL[tid] = ldg_c(&p.eG[b*256 + tid]);
      __syncthreads();
      if (wave == 0){
        float mx = -1e30f;
        for (int i = lane; i < P_; i += 64) mx = fmaxf(mx, eL[i]);
        #pragma unroll
        for (int o = 32; o > 0; o >>= 1) mx = fmaxf(mx, __shfl_xor(mx, o));
        float sum = 0.f;
        for (int i = lane; i < P_; i += 64){
          float ex = __expf(eL[i] - mx);
          alphaL[i] = ex;
          sum += ex;
        }
        #pragma unroll
        for (int o = 32; o > 0; o >>= 1) sum += __shfl_xor(sum, o);
        float inv = 1.f / sum;
        for (int i = lane; i < P_; i += 64) alphaL[i] *= inv;
      }
      __syncthreads();
      {
        bool mb = t < dlb;
        if (tid < 49)
          p.out[OUT_ALPHA + ((size_t)b*T_ + t)*P_ + q*49 + tid] = mb ? alphaL[q*49 + tid] : 0.f;
        if (tid < 25){
          float a0 = alphaL[q*49 + 2*tid];
          float a1 = (2*tid+1 < 49) ? alphaL[q*49 + 2*tid + 1] : 0.f;
          alpha2L[tid] = packh2(a0, a1);
        }
      }
      __syncthreads();
      {
        const unsigned* ec = encT2 + tid*27;
        float s = 0.f;
        #pragma unroll 5
        for (int p2 = 0; p2 < 25; p2++)
          s = fdot2f(ash2(ec[p2]), ash2(alpha2L[p2]), s);
        // deterministic per-q partial (summed in P3 staging) -- no atomics
        stg_c(&p.aweQ[((size_t)b*4 + q)*512 + tid], gateL[tid]*s);
      }
    }
    octbar(p.flb, bt, ct, ++ep);   // B2

    // ======== P3: gates GEMM (MFMA, K=1536) + LSTM ========
    {
      {
        int cc = tid >> 3, r = tid & 7;
        int b8 = bt*8 + r;
        // iter1: emb[cap][cc*8..+8)  (const input, plain loads)
        {
          int cap = p.caps[sbL[r]*L_ + t];
          const float4* er = (const float4*)(p.emb + (size_t)cap*M_ + cc*8);
          float4 f0 = er[0], f1 = er[1];
          uint4 o;
          o.x = packh2(f0.x,f0.y); o.y = packh2(f0.z,f0.w);
          o.z = packh2(f1.x,f1.y); o.w = packh2(f1.z,f1.w);
          xH8_4[tid] = o;
        }
        // iter2: gated awe = sum of 4 q-partials (coherent loads)
        {
          const float* aw = p.aweQ + (size_t)b8*4*512 + cc*8;
          float a8[8];
          #pragma unroll
          for (int e = 0; e < 8; e += 2){
            float2 q0 = ldg2_c(aw + 0*512 + e);
            float2 q1 = ldg2_c(aw + 1*512 + e);
            float2 q2 = ldg2_c(aw + 2*512 + e);
            float2 q3 = ldg2_c(aw + 3*512 + e);
            a8[e]   = (q0.x + q1.x) + (q2.x + q3.x);
            a8[e+1] = (q0.y + q1.y) + (q2.y + q3.y);
          }
          uint4 o;
          o.x = packh2(a8[0],a8[1]); o.y = packh2(a8[2],a8[3]);
          o.z = packh2(a8[4],a8[5]); o.w = packh2(a8[6],a8[7]);
          xH8_4[512 + tid] = o;
        }
        // iter3: h(t)
        {
          const float* hs = hR + (size_t)b8*512 + cc*8;
          float2 v0 = ldg2_c(hs), v1 = ldg2_c(hs+2), v2 = ldg2_c(hs+4), v3 = ldg2_c(hs+6);
          uint4 o;
          o.x = packh2(v0.x,v0.y); o.y = packh2(v1.x,v1.y);
          o.z = packh2(v2.x,v2.y); o.w = packh2(v3.x,v3.y);
          xH8_4[1024 + tid] = o;
        }
      }
      __syncthreads();
      gemv_regs<6>(wg, xH8_4, redW, lane, wave);
      __syncthreads();
      {
        float s = 0.f;
        #pragma unroll
        for (int w8 = 0; w8 < 8; w8++) s += redW[w8*512 + tid];
        gLs[(tid & 7)*64 + (tid >> 3)] = s;
      }
      __syncthreads();
      if (tid < 128){
        int jj = tid >> 3, bb2 = tid & 7;
        int b8 = bt*8 + bb2, jg = ct*16 + jj;
        float g0 = gLs[bb2*64 + jj*4+0] + p.bih[jg]        + p.bhh[jg];
        float g1 = gLs[bb2*64 + jj*4+1] + p.bih[512 + jg]  + p.bhh[512 + jg];
        float g2 = gLs[bb2*64 + jj*4+2] + p.bih[1024 + jg] + p.bhh[1024 + jg];
        float g3 = gLs[bb2*64 + jj*4+3] + p.bih[1536 + jg] + p.bhh[1536 + jg];
        float i_s = sigf(g0), f_s = sigf(g1), g_t = tanhf_(g2), o_s = sigf(g3);
        float c_old = cL[jj*8 + bb2];
        float c_new = f_s*c_old + i_s*g_t;
        float h_new = o_s*tanhf_(c_new);
        bool m = t < sbL[8 + bb2];
        float h_old = ldg_c(&hR[b8*512 + jg]);
        cL[jj*8 + bb2] = m ? c_new : c_old;
        stg_c(&p.hnG[b8*512 + jg], h_new);
        stg_c(&hW[b8*512 + jg], m ? h_new : h_old);
      }
    }
    octbar(p.flb, bt, ct, ++ep);   // B0 (h(t+1), hn(t) published)
  }

  // ---- final preds for t = T-1 ----
  if (ct >= 16){
    {
      int cc = tid >> 3, r = tid & 7;
      const float* src = p.hnG + (size_t)(bt*8 + r)*512 + cc*8;
      float2 v0 = ldg2_c(src), v1 = ldg2_c(src+2), v2 = ldg2_c(src+4), v3 = ldg2_c(src+6);
      uint4 o;
      o.x = packh2(v0.x,v0.y); o.y = packh2(v1.x,v1.y);
      o.z = packh2(v2.x,v2.y); o.w = packh2(v3.x,v3.y);
      xH8_4[tid] = o;
    }
    __syncthreads();
    gemv_regs<2>(wa, xH8_4, redW, lane, wave);
    __syncthreads();
    {
      float s = 0.f;
      #pragma unroll
      for (int w8 = 0; w8 < 8; w8++) s += redW[w8*512 + tid];
      int c_local = tid >> 3, j = tid & 7, b8 = bt*8 + j;
      int v2i = (ct-16)*64 + c_local;
      if (v2i < 1000){
        bool mm = (T_-1) < sbL[8 + j];
        p.out[OUT_PRED + ((size_t)b8*T_ + (T_-1))*V_ + v2i] = mm ? (s + p.fcb[v2i]) : 0.f;
      }
    }
  }
}

extern "C" void kernel_launch(void* const* d_in, const int* in_sizes, int n_in,
                              void* d_out, int out_size, void* d_ws, size_t ws_size,
                              hipStream_t stream){
  (void)in_sizes; (void)n_in; (void)out_size; (void)ws_size;
  KP p;
  p.enc  = (const float*)d_in[0];
  p.caps = (const int*)  d_in[1];
  p.clen = (const int*)  d_in[2];
  p.emb  = (const float*)d_in[3];
  p.eaw  = (const float*)d_in[4];  p.eab = (const float*)d_in[5];
  p.daw  = (const float*)d_in[6];  p.dab = (const float*)d_in[7];
  p.faw  = (const float*)d_in[8];  p.fab = (const float*)d_in[9];
  p.wih  = (const float*)d_in[10]; p.bih = (const float*)d_in[11];
  p.whh  = (const float*)d_in[12]; p.bhh = (const float*)d_in[13];
  p.ihw  = (const float*)d_in[14]; p.ihb = (const float*)d_in[15];
  p.icw  = (const float*)d_in[16]; p.icb = (const float*)d_in[17];
  p.fbw  = (const float*)d_in[18]; p.fbb = (const float*)d_in[19];
  p.fcw  = (const float*)d_in[20]; p.fcb = (const float*)d_in[21];
  p.out  = (float*)d_out;

  char* ws = (char*)d_ws;
  size_t off = 0;
  p.bar = (int*)(ws + off); off += 1024;     // fenced pre-barrier (global)
  p.flb = (int*)(ws + off); off += 8*64*4;   // octet flag barrier
  p.gf  = (int*)(ws + off); off += 64*16*4;  // per-b group flags
  size_t zero_bytes = off;
  p.sort_ind = (int*)(ws + off); off += 64*4;
  p.dec_len  = (int*)(ws + off); off += 64*4;
  off = (off + 255) & ~(size_t)255;
  p.mnT   = (float*)(ws + off); off += (size_t)B_*512*4;
  p.hA    = (float*)(ws + off); off += (size_t)B_*512*4;
  p.hB    = (float*)(ws + off); off += (size_t)B_*512*4;
  p.hnG   = (float*)(ws + off); off += (size_t)B_*512*4;
  p.a2G   = (float*)(ws + off); off += (size_t)B_*512*4;
  p.gateG = (float*)(ws + off); off += (size_t)B_*512*4;
  p.aweQ  = (float*)(ws + off); off += (size_t)B_*4*512*4;
  p.eG    = (float*)(ws + off); off += (size_t)B_*256*4;
  p.att1  = (float*)(ws + off); off += (size_t)B_*P_*A_*4;

  hipMemsetAsync(ws, 0, zero_bytes, stream);

  void* args[] = { (void*)&p };
  hipLaunchCooperativeKernel((const void*)dec_kernel,
                             dim3(NBLK), dim3(NTHR), args, 0, stream);
}